// Round 1
// baseline (5500.257 us; speedup 1.0000x reference)
//
#include <hip/hip_runtime.h>
#include <math.h>

#define DIM 256

// ---------------------------------------------------------------------------
// K1: fused QKV GEMM.  C = h @ [attn_q | attn_k | W^T] (+b on the v part).
// M x 768 output, K = 256.  64x64 tile, 256 threads, 4x4 microtile/thread.
// ---------------------------------------------------------------------------
__global__ __launch_bounds__(256) void gemm_qkv(
    const float* __restrict__ h, const float* __restrict__ attn_q,
    const float* __restrict__ attn_k, const float* __restrict__ W,
    const float* __restrict__ bias,
    float* __restrict__ q, float* __restrict__ k, float* __restrict__ v,
    int M)
{
    __shared__ float As[16][64];   // [k][m]
    __shared__ float Bs[16][64];   // [k][n]

    const int bm = blockIdx.x * 64;
    const int bny = blockIdx.y;          // 0..11
    const int which = bny >> 2;          // 0=q, 1=k, 2=v
    const int bn = (bny & 3) * 64;       // col offset within 256

    const int t  = threadIdx.x;
    const int tx = t & 15;               // n microtile
    const int ty = t >> 4;               // m microtile

    float acc[4][4] = {};

    for (int k0 = 0; k0 < DIM; k0 += 16) {
        // ---- load A tile: 64 rows x 16 k (transposed into LDS) ----
        {
            const int ml = t >> 2;           // 0..63
            const int kq = (t & 3) * 4;      // 0,4,8,12
            const int row = bm + ml;
            float4 av = make_float4(0.f, 0.f, 0.f, 0.f);
            if (row < M) av = *(const float4*)&h[(size_t)row * DIM + k0 + kq];
            As[kq + 0][ml] = av.x; As[kq + 1][ml] = av.y;
            As[kq + 2][ml] = av.z; As[kq + 3][ml] = av.w;
        }
        // ---- load B tile: 16 k x 64 n ----
        {
            const int kk = t >> 4;           // 0..15
            const int nl = (t & 15) * 4;     // 0..60
            if (which == 0) {
                float4 bv = *(const float4*)&attn_q[(size_t)(k0 + kk) * DIM + bn + nl];
                Bs[kk][nl + 0] = bv.x; Bs[kk][nl + 1] = bv.y;
                Bs[kk][nl + 2] = bv.z; Bs[kk][nl + 3] = bv.w;
            } else if (which == 1) {
                float4 bv = *(const float4*)&attn_k[(size_t)(k0 + kk) * DIM + bn + nl];
                Bs[kk][nl + 0] = bv.x; Bs[kk][nl + 1] = bv.y;
                Bs[kk][nl + 2] = bv.z; Bs[kk][nl + 3] = bv.w;
            } else {
                // v part: B[kk][n] = W[(bn+n)*DIM + k0+kk]  (W^T)
                #pragma unroll
                for (int j = 0; j < 4; ++j)
                    Bs[kk][nl + j] = W[(size_t)(bn + nl + j) * DIM + k0 + kk];
            }
        }
        __syncthreads();

        #pragma unroll
        for (int kk = 0; kk < 16; ++kk) {
            float4 ar = *(const float4*)&As[kk][ty * 4];
            float4 br = *(const float4*)&Bs[kk][tx * 4];
            const float arr[4] = {ar.x, ar.y, ar.z, ar.w};
            const float brr[4] = {br.x, br.y, br.z, br.w};
            #pragma unroll
            for (int i = 0; i < 4; ++i)
                #pragma unroll
                for (int j = 0; j < 4; ++j)
                    acc[i][j] += arr[i] * brr[j];
        }
        __syncthreads();
    }

    float* outp = (which == 0) ? q : (which == 1) ? k : v;
    float4 badd = make_float4(0.f, 0.f, 0.f, 0.f);
    if (which == 2) badd = *(const float4*)&bias[bn + tx * 4];

    #pragma unroll
    for (int i = 0; i < 4; ++i) {
        const int row = bm + ty * 4 + i;
        if (row < M) {
            float4 o;
            o.x = acc[i][0] + badd.x;
            o.y = acc[i][1] + badd.y;
            o.z = acc[i][2] + badd.z;
            o.w = acc[i][3] + badd.w;
            *(float4*)&outp[(size_t)row * DIM + bn + tx * 4] = o;
        }
    }
}

// ---------------------------------------------------------------------------
// K2: per-edge raw score (un-scaled dot; scale cancels under standardization)
//     + per-dst degree count + global sum / sumsq (double atomics).
// One 64-lane wave per edge, 4 edges per block.
// ---------------------------------------------------------------------------
__global__ __launch_bounds__(256) void edge_dot(
    const float* __restrict__ q, const float* __restrict__ k,
    const int* __restrict__ src, const int* __restrict__ dst,
    float* __restrict__ a_raw, int* __restrict__ deg,
    double* __restrict__ stats, int E)
{
    const int wid  = threadIdx.x >> 6;
    const int lane = threadIdx.x & 63;
    const int e = blockIdx.x * 4 + wid;

    float dotv = 0.f;
    int d = 0;
    if (e < E) {
        const int s = src[e];
        d = dst[e];
        float4 a4 = ((const float4*)&q[(size_t)s * DIM])[lane];
        float4 b4 = ((const float4*)&k[(size_t)d * DIM])[lane];
        dotv = a4.x * b4.x + a4.y * b4.y + a4.z * b4.z + a4.w * b4.w;
    }
    #pragma unroll
    for (int off = 32; off; off >>= 1) dotv += __shfl_down(dotv, off);

    __shared__ float bsum[4], bsum2[4];
    if (lane == 0) {
        const float val = (e < E) ? dotv : 0.f;
        bsum[wid]  = val;
        bsum2[wid] = val * val;
        if (e < E) {
            a_raw[e] = dotv;
            atomicAdd(&deg[d], 1);
        }
    }
    __syncthreads();
    if (threadIdx.x == 0) {
        atomicAdd(&stats[0], (double)(bsum[0] + bsum[1] + bsum[2] + bsum[3]));
        atomicAdd(&stats[1], (double)(bsum2[0] + bsum2[1] + bsum2[2] + bsum2[3]));
    }
}

// ---------------------------------------------------------------------------
// K3: single-block: finalize stats -> (mean, mul) and prefix-scan deg -> row_ptr
// ---------------------------------------------------------------------------
__global__ __launch_bounds__(1024) void scan_rowptr(
    const int* __restrict__ deg, int* __restrict__ row_ptr, int N,
    const double* __restrict__ stats, float* __restrict__ coef, int E)
{
    if (threadIdx.x == 0) {
        const double mean = stats[0] / (double)E;
        const double var  = stats[1] / (double)E - mean * mean;
        coef[0] = (float)mean;
        coef[1] = (float)(1.0 / (sqrt(var) * 0.5));   // x2 = /TEMPERATURE
        row_ptr[0] = 0;
    }
    __shared__ int buf[1024];
    __shared__ int carry;
    if (threadIdx.x == 0) carry = 0;
    __syncthreads();

    for (int base = 0; base < N; base += 1024) {
        const int i = base + threadIdx.x;
        buf[threadIdx.x] = (i < N) ? deg[i] : 0;
        __syncthreads();
        for (int off = 1; off < 1024; off <<= 1) {
            int y = (threadIdx.x >= off) ? buf[threadIdx.x - off] : 0;
            __syncthreads();
            buf[threadIdx.x] += y;
            __syncthreads();
        }
        const int total = buf[1023];
        if (i < N) row_ptr[i + 1] = carry + buf[threadIdx.x];
        __syncthreads();
        if (threadIdx.x == 0) carry += total;
        __syncthreads();
    }
}

// ---------------------------------------------------------------------------
// K4: scatter edge ids into CSR order
// ---------------------------------------------------------------------------
__global__ __launch_bounds__(256) void scatter_edges(
    const int* __restrict__ dst, const int* __restrict__ row_ptr,
    int* __restrict__ cursor, int* __restrict__ edge_idx, int E)
{
    const int e = blockIdx.x * 256 + threadIdx.x;
    if (e < E) {
        const int d = dst[e];
        const int pos = atomicAdd(&cursor[d], 1);
        edge_idx[row_ptr[d] + pos] = e;
    }
}

// ---------------------------------------------------------------------------
// K5: per-dst edge softmax over standardized scores; writes final a (output)
// One wave per node, 4 nodes per block.
// ---------------------------------------------------------------------------
__global__ __launch_bounds__(256) void edge_softmax(
    const float* __restrict__ a_raw, const int* __restrict__ row_ptr,
    const int* __restrict__ edge_idx, const float* __restrict__ coef,
    float* __restrict__ a_out, int N)
{
    const int wid  = threadIdx.x >> 6;
    const int lane = threadIdx.x & 63;
    const int node = blockIdx.x * 4 + wid;
    if (node >= N) return;

    const int s  = row_ptr[node];
    const int en = row_ptr[node + 1];
    const float mean = coef[0];
    const float mul  = coef[1];

    float mx = -INFINITY;
    for (int j = s + lane; j < en; j += 64)
        mx = fmaxf(mx, (a_raw[edge_idx[j]] - mean) * mul);
    #pragma unroll
    for (int off = 32; off; off >>= 1) mx = fmaxf(mx, __shfl_xor(mx, off));

    float sum = 0.f;
    for (int j = s + lane; j < en; j += 64)
        sum += __expf((a_raw[edge_idx[j]] - mean) * mul - mx);
    #pragma unroll
    for (int off = 32; off; off >>= 1) sum += __shfl_xor(sum, off);

    const float rcp = 1.0f / sum;
    for (int j = s + lane; j < en; j += 64) {
        const int e = edge_idx[j];
        a_out[e] = __expf((a_raw[e] - mean) * mul - mx) * rcp;
    }
}

// ---------------------------------------------------------------------------
// K6: per-node aggregation: out[i,:] = sum_e a_e * v[src_e,:]
// One 256-thread block per node; thread = column. Gather, no atomics.
// ---------------------------------------------------------------------------
__global__ __launch_bounds__(256) void aggregate(
    const float* __restrict__ v, const float* __restrict__ a_out,
    const int* __restrict__ src, const int* __restrict__ row_ptr,
    const int* __restrict__ edge_idx, float* __restrict__ out, int N)
{
    const int node = blockIdx.x;
    const int col  = threadIdx.x;
    const int s  = row_ptr[node];
    const int en = row_ptr[node + 1];

    __shared__ float ae[64];
    __shared__ int   asrc[64];

    float acc = 0.f;
    for (int base = s; base < en; base += 64) {
        const int cnt = min(64, en - base);
        if (threadIdx.x < cnt) {
            const int e = edge_idx[base + threadIdx.x];
            ae[threadIdx.x]   = a_out[e];
            asrc[threadIdx.x] = src[e];
        }
        __syncthreads();
        for (int j = 0; j < cnt; ++j)
            acc += ae[j] * v[(size_t)asrc[j] * DIM + col];
        __syncthreads();
    }
    out[(size_t)node * DIM + col] = acc;
}

// ---------------------------------------------------------------------------
extern "C" void kernel_launch(void* const* d_in, const int* in_sizes, int n_in,
                              void* d_out, int out_size, void* d_ws, size_t ws_size,
                              hipStream_t stream)
{
    const float* h      = (const float*)d_in[0];
    const int*   src    = (const int*)d_in[1];
    const int*   dst    = (const int*)d_in[2];
    const float* attn_q = (const float*)d_in[3];
    const float* attn_k = (const float*)d_in[4];
    const float* W      = (const float*)d_in[5];
    const float* bias   = (const float*)d_in[6];

    const int N = in_sizes[0] / DIM;
    const int E = in_sizes[1];

    float* out   = (float*)d_out;
    float* a_out = out + (size_t)N * DIM;

    char* ws = (char*)d_ws;
    float* q      = (float*)ws; ws += (size_t)N * DIM * 4;
    float* k      = (float*)ws; ws += (size_t)N * DIM * 4;
    float* v      = (float*)ws; ws += (size_t)N * DIM * 4;
    float* a_raw  = (float*)ws; ws += (size_t)E * 4;
    int* edge_idx = (int*)ws;   ws += (size_t)E * 4;
    int* deg      = (int*)ws;   ws += (size_t)N * 4;
    int* cursor   = (int*)ws;   ws += (size_t)N * 4;
    double* stats = (double*)ws; ws += 16;
    float* coef   = (float*)ws;  ws += 8;
    int* row_ptr  = (int*)ws;    ws += (size_t)(N + 1) * 4;

    hipMemsetAsync(deg,    0, (size_t)N * 4, stream);
    hipMemsetAsync(cursor, 0, (size_t)N * 4, stream);
    hipMemsetAsync(stats,  0, 16, stream);

    dim3 gg((N + 63) / 64, 12);
    gemm_qkv<<<gg, 256, 0, stream>>>(h, attn_q, attn_k, W, bias, q, k, v, N);
    edge_dot<<<(E + 3) / 4, 256, 0, stream>>>(q, k, src, dst, a_raw, deg, stats, E);
    scan_rowptr<<<1, 1024, 0, stream>>>(deg, row_ptr, N, stats, coef, E);
    scatter_edges<<<(E + 255) / 256, 256, 0, stream>>>(dst, row_ptr, cursor, edge_idx, E);
    edge_softmax<<<(N + 3) / 4, 256, 0, stream>>>(a_raw, row_ptr, edge_idx, coef, a_out, N);
    aggregate<<<N, 256, 0, stream>>>(v, a_out, src, row_ptr, edge_idx, out, N);
}

// Round 4
// 898.313 us; speedup vs baseline: 6.1229x; 6.1229x over previous
//
#include <hip/hip_runtime.h>
#include <math.h>

#define DIM 256
#define STAT_BLOCKS 2048

// ---------------------------------------------------------------------------
// K1: fused QKV GEMM.  C = h @ [attn_q | attn_k | W^T] (+b on the v part).
// M x 768 output, K = 256.  64x64 tile, 256 threads, 4x4 microtile/thread.
// ---------------------------------------------------------------------------
__global__ __launch_bounds__(256) void gemm_qkv(
    const float* __restrict__ h, const float* __restrict__ attn_q,
    const float* __restrict__ attn_k, const float* __restrict__ W,
    const float* __restrict__ bias,
    float* __restrict__ q, float* __restrict__ k, float* __restrict__ v,
    int M)
{
    __shared__ float As[16][64];   // [k][m]
    __shared__ float Bs[16][64];   // [k][n]

    const int bm = blockIdx.x * 64;
    const int bny = blockIdx.y;          // 0..11
    const int which = bny >> 2;          // 0=q, 1=k, 2=v
    const int bn = (bny & 3) * 64;       // col offset within 256

    const int t  = threadIdx.x;
    const int tx = t & 15;               // n microtile
    const int ty = t >> 4;               // m microtile

    float acc[4][4] = {};

    for (int k0 = 0; k0 < DIM; k0 += 16) {
        // ---- load A tile: 64 rows x 16 k (transposed into LDS) ----
        {
            const int ml = t >> 2;           // 0..63
            const int kq = (t & 3) * 4;      // 0,4,8,12
            const int row = bm + ml;
            float4 av = make_float4(0.f, 0.f, 0.f, 0.f);
            if (row < M) av = *(const float4*)&h[(size_t)row * DIM + k0 + kq];
            As[kq + 0][ml] = av.x; As[kq + 1][ml] = av.y;
            As[kq + 2][ml] = av.z; As[kq + 3][ml] = av.w;
        }
        // ---- load B tile: 16 k x 64 n ----
        {
            const int kk = t >> 4;           // 0..15
            const int nl = (t & 15) * 4;     // 0..60
            if (which == 0) {
                float4 bv = *(const float4*)&attn_q[(size_t)(k0 + kk) * DIM + bn + nl];
                Bs[kk][nl + 0] = bv.x; Bs[kk][nl + 1] = bv.y;
                Bs[kk][nl + 2] = bv.z; Bs[kk][nl + 3] = bv.w;
            } else if (which == 1) {
                float4 bv = *(const float4*)&attn_k[(size_t)(k0 + kk) * DIM + bn + nl];
                Bs[kk][nl + 0] = bv.x; Bs[kk][nl + 1] = bv.y;
                Bs[kk][nl + 2] = bv.z; Bs[kk][nl + 3] = bv.w;
            } else {
                // v part: B[kk][n] = W[(bn+n)*DIM + k0+kk]  (W^T)
                #pragma unroll
                for (int j = 0; j < 4; ++j)
                    Bs[kk][nl + j] = W[(size_t)(bn + nl + j) * DIM + k0 + kk];
            }
        }
        __syncthreads();

        #pragma unroll
        for (int kk = 0; kk < 16; ++kk) {
            float4 ar = *(const float4*)&As[kk][ty * 4];
            float4 br = *(const float4*)&Bs[kk][tx * 4];
            const float arr[4] = {ar.x, ar.y, ar.z, ar.w};
            const float brr[4] = {br.x, br.y, br.z, br.w};
            #pragma unroll
            for (int i = 0; i < 4; ++i)
                #pragma unroll
                for (int j = 0; j < 4; ++j)
                    acc[i][j] += arr[i] * brr[j];
        }
        __syncthreads();
    }

    float* outp = (which == 0) ? q : (which == 1) ? k : v;
    float4 badd = make_float4(0.f, 0.f, 0.f, 0.f);
    if (which == 2) badd = *(const float4*)&bias[bn + tx * 4];

    #pragma unroll
    for (int i = 0; i < 4; ++i) {
        const int row = bm + ty * 4 + i;
        if (row < M) {
            float4 o;
            o.x = acc[i][0] + badd.x;
            o.y = acc[i][1] + badd.y;
            o.z = acc[i][2] + badd.z;
            o.w = acc[i][3] + badd.w;
            *(float4*)&outp[(size_t)row * DIM + bn + tx * 4] = o;
        }
    }
}

// ---------------------------------------------------------------------------
// K2: per-edge raw score (un-scaled dot; scale cancels under standardization)
//     + per-dst degree count.  Grid-stride, one wave per edge-iteration.
//     Per-block partial sum/sumsq written to partials[] — NO stats atomics.
// ---------------------------------------------------------------------------
__global__ __launch_bounds__(256) void edge_dot(
    const float* __restrict__ q, const float* __restrict__ k,
    const int* __restrict__ src, const int* __restrict__ dst,
    float* __restrict__ a_raw, int* __restrict__ deg,
    double* __restrict__ partials, int E)
{
    const int wid  = threadIdx.x >> 6;
    const int lane = threadIdx.x & 63;
    const int nwaves = gridDim.x * 4;

    double lsum = 0.0, lsum2 = 0.0;
    for (int e = blockIdx.x * 4 + wid; e < E; e += nwaves) {
        const int s = src[e];
        const int d = dst[e];
        float4 a4 = ((const float4*)&q[(size_t)s * DIM])[lane];
        float4 b4 = ((const float4*)&k[(size_t)d * DIM])[lane];
        float dotv = a4.x * b4.x + a4.y * b4.y + a4.z * b4.z + a4.w * b4.w;
        #pragma unroll
        for (int off = 32; off; off >>= 1) dotv += __shfl_xor(dotv, off);
        if (lane == 0) {
            a_raw[e] = dotv;
            atomicAdd(&deg[d], 1);
            lsum  += (double)dotv;
            lsum2 += (double)dotv * (double)dotv;
        }
    }

    __shared__ double bsum[4], bsum2[4];
    if (lane == 0) { bsum[wid] = lsum; bsum2[wid] = lsum2; }
    __syncthreads();
    if (threadIdx.x == 0) {
        partials[blockIdx.x]              = bsum[0] + bsum[1] + bsum[2] + bsum[3];
        partials[gridDim.x + blockIdx.x]  = bsum2[0] + bsum2[1] + bsum2[2] + bsum2[3];
    }
}

// ---------------------------------------------------------------------------
// K3: single-block: reduce partials -> (mean, mul); prefix-scan deg -> row_ptr
// ---------------------------------------------------------------------------
__global__ __launch_bounds__(1024) void scan_rowptr(
    const int* __restrict__ deg, int* __restrict__ row_ptr, int N,
    const double* __restrict__ partials, float* __restrict__ coef, int E)
{
    // ---- reduce the per-block stat partials ----
    __shared__ double red[1024];
    double s1 = 0.0, s2 = 0.0;
    for (int i = threadIdx.x; i < STAT_BLOCKS; i += 1024) {
        s1 += partials[i];
        s2 += partials[STAT_BLOCKS + i];
    }
    red[threadIdx.x] = s1;
    __syncthreads();
    for (int off = 512; off; off >>= 1) {
        if (threadIdx.x < off) red[threadIdx.x] += red[threadIdx.x + off];
        __syncthreads();
    }
    const double tot1 = red[0];
    __syncthreads();
    red[threadIdx.x] = s2;
    __syncthreads();
    for (int off = 512; off; off >>= 1) {
        if (threadIdx.x < off) red[threadIdx.x] += red[threadIdx.x + off];
        __syncthreads();
    }
    const double tot2 = red[0];
    __syncthreads();

    if (threadIdx.x == 0) {
        const double mean = tot1 / (double)E;
        const double var  = tot2 / (double)E - mean * mean;
        coef[0] = (float)mean;
        coef[1] = (float)(1.0 / (sqrt(var) * 0.5));   // /std /TEMPERATURE
        row_ptr[0] = 0;
    }

    // ---- prefix scan of degrees ----
    __shared__ int buf[1024];
    __shared__ int carry;
    if (threadIdx.x == 0) carry = 0;
    __syncthreads();

    for (int base = 0; base < N; base += 1024) {
        const int i = base + threadIdx.x;
        buf[threadIdx.x] = (i < N) ? deg[i] : 0;
        __syncthreads();
        for (int off = 1; off < 1024; off <<= 1) {
            int y = (threadIdx.x >= off) ? buf[threadIdx.x - off] : 0;
            __syncthreads();
            buf[threadIdx.x] += y;
            __syncthreads();
        }
        const int total = buf[1023];
        if (i < N) row_ptr[i + 1] = carry + buf[threadIdx.x];
        __syncthreads();
        if (threadIdx.x == 0) carry += total;
        __syncthreads();
    }
}

// ---------------------------------------------------------------------------
// K4: scatter edge ids into CSR order
// ---------------------------------------------------------------------------
__global__ __launch_bounds__(256) void scatter_edges(
    const int* __restrict__ dst, const int* __restrict__ row_ptr,
    int* __restrict__ cursor, int* __restrict__ edge_idx, int E)
{
    const int e = blockIdx.x * 256 + threadIdx.x;
    if (e < E) {
        const int d = dst[e];
        const int pos = atomicAdd(&cursor[d], 1);
        edge_idx[row_ptr[d] + pos] = e;
    }
}

// ---------------------------------------------------------------------------
// K5: per-dst edge softmax over standardized scores; writes final a (output)
// One wave per node, 4 nodes per block.
// ---------------------------------------------------------------------------
__global__ __launch_bounds__(256) void edge_softmax(
    const float* __restrict__ a_raw, const int* __restrict__ row_ptr,
    const int* __restrict__ edge_idx, const float* __restrict__ coef,
    float* __restrict__ a_out, int N)
{
    const int wid  = threadIdx.x >> 6;
    const int lane = threadIdx.x & 63;
    const int node = blockIdx.x * 4 + wid;
    if (node >= N) return;

    const int s  = row_ptr[node];
    const int en = row_ptr[node + 1];
    const float mean = coef[0];
    const float mul  = coef[1];

    float mx = -INFINITY;
    for (int j = s + lane; j < en; j += 64)
        mx = fmaxf(mx, (a_raw[edge_idx[j]] - mean) * mul);
    #pragma unroll
    for (int off = 32; off; off >>= 1) mx = fmaxf(mx, __shfl_xor(mx, off));

    float sum = 0.f;
    for (int j = s + lane; j < en; j += 64)
        sum += __expf((a_raw[edge_idx[j]] - mean) * mul - mx);
    #pragma unroll
    for (int off = 32; off; off >>= 1) sum += __shfl_xor(sum, off);

    const float rcp = 1.0f / sum;
    for (int j = s + lane; j < en; j += 64) {
        const int e = edge_idx[j];
        a_out[e] = __expf((a_raw[e] - mean) * mul - mx) * rcp;
    }
}

// ---------------------------------------------------------------------------
// K6: per-node aggregation: out[i,:] = sum_e a_e * v[src_e,:]
// One 256-thread block per node; thread = column. Gather, no atomics.
// ---------------------------------------------------------------------------
__global__ __launch_bounds__(256) void aggregate(
    const float* __restrict__ v, const float* __restrict__ a_out,
    const int* __restrict__ src, const int* __restrict__ row_ptr,
    const int* __restrict__ edge_idx, float* __restrict__ out, int N)
{
    const int node = blockIdx.x;
    const int col  = threadIdx.x;
    const int s  = row_ptr[node];
    const int en = row_ptr[node + 1];

    __shared__ float ae[64];
    __shared__ int   asrc[64];

    float acc = 0.f;
    for (int base = s; base < en; base += 64) {
        const int cnt = min(64, en - base);
        if (threadIdx.x < cnt) {
            const int e = edge_idx[base + threadIdx.x];
            ae[threadIdx.x]   = a_out[e];
            asrc[threadIdx.x] = src[e];
        }
        __syncthreads();
        for (int j = 0; j < cnt; ++j)
            acc += ae[j] * v[(size_t)asrc[j] * DIM + col];
        __syncthreads();
    }
    out[(size_t)node * DIM + col] = acc;
}

// ---------------------------------------------------------------------------
extern "C" void kernel_launch(void* const* d_in, const int* in_sizes, int n_in,
                              void* d_out, int out_size, void* d_ws, size_t ws_size,
                              hipStream_t stream)
{
    const float* h      = (const float*)d_in[0];
    const int*   src    = (const int*)d_in[1];
    const int*   dst    = (const int*)d_in[2];
    const float* attn_q = (const float*)d_in[3];
    const float* attn_k = (const float*)d_in[4];
    const float* W      = (const float*)d_in[5];
    const float* bias   = (const float*)d_in[6];

    const int N = in_sizes[0] / DIM;
    const int E = in_sizes[1];

    float* out   = (float*)d_out;
    float* a_out = out + (size_t)N * DIM;

    char* ws = (char*)d_ws;
    float* q      = (float*)ws; ws += (size_t)N * DIM * 4;
    float* k      = (float*)ws; ws += (size_t)N * DIM * 4;
    float* v      = (float*)ws; ws += (size_t)N * DIM * 4;
    float* a_raw  = (float*)ws; ws += (size_t)E * 4;
    int* edge_idx = (int*)ws;   ws += (size_t)E * 4;
    int* deg      = (int*)ws;   ws += (size_t)N * 4;
    int* cursor   = (int*)ws;   ws += (size_t)N * 4;
    double* partials = (double*)ws; ws += (size_t)STAT_BLOCKS * 2 * 8;
    float* coef   = (float*)ws;  ws += 8;
    int* row_ptr  = (int*)ws;    ws += (size_t)(N + 1) * 4;

    hipMemsetAsync(deg,    0, (size_t)N * 4, stream);
    hipMemsetAsync(cursor, 0, (size_t)N * 4, stream);

    dim3 gg((N + 63) / 64, 12);
    gemm_qkv<<<gg, 256, 0, stream>>>(h, attn_q, attn_k, W, bias, q, k, v, N);
    edge_dot<<<STAT_BLOCKS, 256, 0, stream>>>(q, k, src, dst, a_raw, deg, partials, E);
    scan_rowptr<<<1, 1024, 0, stream>>>(deg, row_ptr, N, partials, coef, E);
    scatter_edges<<<(E + 255) / 256, 256, 0, stream>>>(dst, row_ptr, cursor, edge_idx, E);
    edge_softmax<<<(N + 3) / 4, 256, 0, stream>>>(a_raw, row_ptr, edge_idx, coef, a_out, N);
    aggregate<<<N, 256, 0, stream>>>(v, a_out, src, row_ptr, edge_idx, out, N);
}

// Round 5
// 508.696 us; speedup vs baseline: 10.8125x; 1.7659x over previous
//
#include <hip/hip_runtime.h>
#include <math.h>

#define DIM 256
#define NQKV 768
#define STAT_BLOCKS 2048

typedef float  f32x4 __attribute__((ext_vector_type(4)));
typedef short  bs8   __attribute__((ext_vector_type(8)));

__device__ __forceinline__ ushort f2bf(float f) {
    unsigned int u = __float_as_uint(f);
    u += 0x7fffu + ((u >> 16) & 1u);
    return (ushort)(u >> 16);
}
__device__ __forceinline__ float bf2f(ushort u) {
    return __uint_as_float(((unsigned int)u) << 16);
}

// v_mfma with s_nop 1 prefix (covers VALU-write -> MFMA-read hazard; compiler
// cannot see through inline asm).  16x16x32 bf16: a,b = 8 bf16 (4 VGPR), c = 4 f32.
#define MFMA16(c, a, b) \
    asm("s_nop 1\n\tv_mfma_f32_16x16x32_bf16 %0, %1, %2, %0" : "+v"(c) : "v"(a), "v"(b))

// ---------------------------------------------------------------------------
// K0a: h (f32) -> h_bf (bf16), 8 elems/thread
// ---------------------------------------------------------------------------
__global__ __launch_bounds__(256) void conv_h(
    const float* __restrict__ h, ushort* __restrict__ h_bf, int total8)
{
    const int idx = blockIdx.x * 256 + threadIdx.x;
    if (idx >= total8) return;
    const float4* hp = (const float4*)(h + (size_t)idx * 8);
    float4 a = hp[0], b = hp[1];
    uint4 o;
    o.x = (unsigned)f2bf(a.x) | ((unsigned)f2bf(a.y) << 16);
    o.y = (unsigned)f2bf(a.z) | ((unsigned)f2bf(a.w) << 16);
    o.z = (unsigned)f2bf(b.x) | ((unsigned)f2bf(b.y) << 16);
    o.w = (unsigned)f2bf(b.z) | ((unsigned)f2bf(b.w) << 16);
    *(uint4*)(h_bf + (size_t)idx * 8) = o;
}

// ---------------------------------------------------------------------------
// K0b: build BmatT [768][256] bf16:  col-major combined weights.
//  n<256: attn_q[k][n]; n<512: attn_k[k][n-256]; n>=512: W[n-512][k]
// ---------------------------------------------------------------------------
__global__ __launch_bounds__(256) void build_bt(
    const float* __restrict__ attn_q, const float* __restrict__ attn_k,
    const float* __restrict__ W, ushort* __restrict__ bt)
{
    const int n = blockIdx.x;
    const int k = threadIdx.x;
    float val;
    if (n < 256)      val = attn_q[(size_t)k * 256 + n];
    else if (n < 512) val = attn_k[(size_t)k * 256 + (n - 256)];
    else              val = W[(size_t)(n - 512) * 256 + k];
    bt[(size_t)n * 256 + k] = f2bf(val);
}

// ---------------------------------------------------------------------------
// K1: MFMA GEMM:  qkv[M][768] (bf16) = h_bf[M][256] @ BmatT^T  (+bias on v)
// Block 128x128, 4 waves (2x2), each wave 64x64 = 4x4 frags of 16x16.
// LDS rows padded to 80B -> <=2-way bank conflicts on ds_read_b128.
// ---------------------------------------------------------------------------
__global__ __launch_bounds__(256) void gemm_qkv_mfma(
    const ushort* __restrict__ h_bf, const ushort* __restrict__ bt,
    const float* __restrict__ bias, ushort* __restrict__ qkv, int M)
{
    __shared__ __align__(16) ushort As[128 * 40];   // [row][40]  (80B rows)
    __shared__ __align__(16) ushort Bs[128 * 40];   // [col][40]

    const int bm = blockIdx.x * 128;
    const int bn = blockIdx.y * 128;
    const int t    = threadIdx.x;
    const int lane = t & 63;
    const int wid  = t >> 6;
    const int wm   = wid >> 1;       // 0..1
    const int wn   = wid & 1;        // 0..1
    const int fr   = lane & 15;      // frag row/col
    const int ko   = (lane >> 4) * 8; // k-element offset of this lane's 8 elems

    f32x4 acc[4][4];
    #pragma unroll
    for (int i = 0; i < 4; ++i)
        #pragma unroll
        for (int j = 0; j < 4; ++j)
            acc[i][j] = (f32x4){0.f, 0.f, 0.f, 0.f};

    for (int k0 = 0; k0 < DIM; k0 += 32) {
        // ---- stage A and B tiles: 128 rows x 32 k (bf16), 16B per chunk ----
        #pragma unroll
        for (int ii = 0; ii < 2; ++ii) {
            const int s   = t * 2 + ii;        // 0..511
            const int row = s >> 2;
            const int sl  = s & 3;             // 16B slot within row
            int ga = bm + row; if (ga > M - 1) ga = M - 1;
            uint4 va = *(const uint4*)(h_bf + (size_t)ga * 256 + k0 + sl * 8);
            *(uint4*)(As + row * 40 + sl * 8) = va;
            uint4 vb = *(const uint4*)(bt + (size_t)(bn + row) * 256 + k0 + sl * 8);
            *(uint4*)(Bs + row * 40 + sl * 8) = vb;
        }
        __syncthreads();

        bs8 af[4], bf_[4];
        #pragma unroll
        for (int f = 0; f < 4; ++f) {
            af[f]  = *(const bs8*)(As + (wm * 64 + f * 16 + fr) * 40 + ko);
            bf_[f] = *(const bs8*)(Bs + (wn * 64 + f * 16 + fr) * 40 + ko);
        }
        #pragma unroll
        for (int fm = 0; fm < 4; ++fm)
            #pragma unroll
            for (int fn = 0; fn < 4; ++fn)
                MFMA16(acc[fm][fn], af[fm], bf_[fn]);

        __syncthreads();
    }

    // XDL -> VALU read hazard padding (inline asm hides MFMA from compiler)
    asm volatile("s_nop 7\n\ts_nop 7\n\ts_nop 7" ::: );

    // ---- epilogue: C frag layout col=lane&15, row=(lane>>4)*4+reg ----
    #pragma unroll
    for (int fm = 0; fm < 4; ++fm) {
        const int rowbase = bm + wm * 64 + fm * 16 + (lane >> 4) * 4;
        #pragma unroll
        for (int fn = 0; fn < 4; ++fn) {
            const int col = bn + wn * 64 + fn * 16 + fr;
            float bv = (col >= 512) ? bias[col - 512] : 0.f;
            #pragma unroll
            for (int r = 0; r < 4; ++r) {
                const int row = rowbase + r;
                if (row < M)
                    qkv[(size_t)row * NQKV + col] = f2bf(acc[fm][fn][r] + bv);
            }
        }
    }
}

// ---------------------------------------------------------------------------
// K2: per-edge raw score from bf16 q,k rows (512B gathers) + degree count
//     + per-block stat partials (no global stat atomics).
// ---------------------------------------------------------------------------
__global__ __launch_bounds__(256) void edge_dot(
    const ushort* __restrict__ qkv,
    const int* __restrict__ src, const int* __restrict__ dst,
    float* __restrict__ a_raw, int* __restrict__ deg,
    double* __restrict__ partials, int E)
{
    const int wid  = threadIdx.x >> 6;
    const int lane = threadIdx.x & 63;
    const int nwaves = gridDim.x * 4;

    double lsum = 0.0, lsum2 = 0.0;
    for (int e = blockIdx.x * 4 + wid; e < E; e += nwaves) {
        const int s = src[e];
        const int d = dst[e];
        ushort4 qa = *(const ushort4*)(qkv + (size_t)s * NQKV + lane * 4);
        ushort4 kb = *(const ushort4*)(qkv + (size_t)d * NQKV + 256 + lane * 4);
        float dotv = bf2f(qa.x) * bf2f(kb.x) + bf2f(qa.y) * bf2f(kb.y)
                   + bf2f(qa.z) * bf2f(kb.z) + bf2f(qa.w) * bf2f(kb.w);
        #pragma unroll
        for (int off = 32; off; off >>= 1) dotv += __shfl_xor(dotv, off);
        if (lane == 0) {
            a_raw[e] = dotv;
            atomicAdd(&deg[d], 1);
            lsum  += (double)dotv;
            lsum2 += (double)dotv * (double)dotv;
        }
    }

    __shared__ double bsum[4], bsum2[4];
    if (lane == 0) { bsum[wid] = lsum; bsum2[wid] = lsum2; }
    __syncthreads();
    if (threadIdx.x == 0) {
        partials[blockIdx.x]             = bsum[0] + bsum[1] + bsum[2] + bsum[3];
        partials[gridDim.x + blockIdx.x] = bsum2[0] + bsum2[1] + bsum2[2] + bsum2[3];
    }
}

// ---------------------------------------------------------------------------
// K3: single block: reduce stat partials -> coef; shuffle-scan deg -> row_ptr
// (4096-elem chunks, 3 barriers/chunk instead of 10/1024)
// ---------------------------------------------------------------------------
__global__ __launch_bounds__(1024) void scan_rowptr(
    const int* __restrict__ deg, int* __restrict__ row_ptr, int N,
    const double* __restrict__ partials, float* __restrict__ coef, int E)
{
    const int tid  = threadIdx.x;
    const int lane = tid & 63;
    const int wv   = tid >> 6;       // 16 waves

    // ---- stats ----
    __shared__ double red[1024];
    double s1 = 0.0, s2 = 0.0;
    for (int i = tid; i < STAT_BLOCKS; i += 1024) {
        s1 += partials[i];
        s2 += partials[STAT_BLOCKS + i];
    }
    red[tid] = s1;
    __syncthreads();
    for (int off = 512; off; off >>= 1) {
        if (tid < off) red[tid] += red[tid + off];
        __syncthreads();
    }
    const double tot1 = red[0];
    __syncthreads();
    red[tid] = s2;
    __syncthreads();
    for (int off = 512; off; off >>= 1) {
        if (tid < off) red[tid] += red[tid + off];
        __syncthreads();
    }
    const double tot2 = red[0];
    __syncthreads();

    if (tid == 0) {
        const double mean = tot1 / (double)E;
        const double var  = tot2 / (double)E - mean * mean;
        coef[0] = (float)mean;
        coef[1] = (float)(1.0 / (sqrt(var) * 0.5));   // /std /TEMPERATURE
        row_ptr[0] = 0;
    }

    // ---- scan ----
    __shared__ int woff[17];
    __shared__ int carryS;
    if (tid == 0) carryS = 0;
    __syncthreads();

    for (int base = 0; base < N; base += 4096) {
        int x[4], pre[4];
        int run = 0;
        #pragma unroll
        for (int j = 0; j < 4; ++j) {
            const int i = base + tid * 4 + j;
            const int v = (i < N) ? deg[i] : 0;
            pre[j] = run; x[j] = v; run += v;
        }
        int incl = run;
        #pragma unroll
        for (int off = 1; off < 64; off <<= 1) {
            int y = __shfl_up(incl, off);
            if (lane >= off) incl += y;
        }
        const int wex = incl - run;
        if (lane == 63) woff[wv] = incl;
        __syncthreads();
        if (wv == 0) {
            int wtot = (lane < 16) ? woff[lane] : 0;
            int winc = wtot;
            #pragma unroll
            for (int off = 1; off < 16; off <<= 1) {
                int y = __shfl_up(winc, off);
                if (lane >= off) winc += y;
            }
            if (lane < 16) woff[lane] = winc - wtot;
            if (lane == 15) woff[16] = winc;
        }
        __syncthreads();
        const int basev = carryS + woff[wv] + wex;
        #pragma unroll
        for (int j = 0; j < 4; ++j) {
            const int i = base + tid * 4 + j;
            if (i < N) row_ptr[i + 1] = basev + pre[j] + x[j];
        }
        __syncthreads();
        if (tid == 0) carryS += woff[16];
        __syncthreads();
    }
}

// ---------------------------------------------------------------------------
// K4: scatter edge ids into CSR order
// ---------------------------------------------------------------------------
__global__ __launch_bounds__(256) void scatter_edges(
    const int* __restrict__ dst, const int* __restrict__ row_ptr,
    int* __restrict__ cursor, int* __restrict__ edge_idx, int E)
{
    const int e = blockIdx.x * 256 + threadIdx.x;
    if (e < E) {
        const int d = dst[e];
        const int pos = atomicAdd(&cursor[d], 1);
        edge_idx[row_ptr[d] + pos] = e;
    }
}

// ---------------------------------------------------------------------------
// K5: per-dst edge softmax; writes final a (output)
// ---------------------------------------------------------------------------
__global__ __launch_bounds__(256) void edge_softmax(
    const float* __restrict__ a_raw, const int* __restrict__ row_ptr,
    const int* __restrict__ edge_idx, const float* __restrict__ coef,
    float* __restrict__ a_out, int N)
{
    const int wid  = threadIdx.x >> 6;
    const int lane = threadIdx.x & 63;
    const int node = blockIdx.x * 4 + wid;
    if (node >= N) return;

    const int s  = row_ptr[node];
    const int en = row_ptr[node + 1];
    const float mean = coef[0];
    const float mul  = coef[1];

    float mx = -INFINITY;
    for (int j = s + lane; j < en; j += 64)
        mx = fmaxf(mx, (a_raw[edge_idx[j]] - mean) * mul);
    #pragma unroll
    for (int off = 32; off; off >>= 1) mx = fmaxf(mx, __shfl_xor(mx, off));

    float sum = 0.f;
    for (int j = s + lane; j < en; j += 64)
        sum += __expf((a_raw[edge_idx[j]] - mean) * mul - mx);
    #pragma unroll
    for (int off = 32; off; off >>= 1) sum += __shfl_xor(sum, off);

    const float rcp = 1.0f / sum;
    for (int j = s + lane; j < en; j += 64) {
        const int e = edge_idx[j];
        a_out[e] = __expf((a_raw[e] - mean) * mul - mx) * rcp;
    }
}

// ---------------------------------------------------------------------------
// K6: per-node aggregation from bf16 v rows: out[i,:] = sum a_e * v[src_e,:]
// ---------------------------------------------------------------------------
__global__ __launch_bounds__(256) void aggregate(
    const ushort* __restrict__ qkv, const float* __restrict__ a_out,
    const int* __restrict__ src, const int* __restrict__ row_ptr,
    const int* __restrict__ edge_idx, float* __restrict__ out, int N)
{
    const int node = blockIdx.x;
    const int col  = threadIdx.x;
    const int s  = row_ptr[node];
    const int en = row_ptr[node + 1];

    __shared__ float ae[64];
    __shared__ int   asrc[64];

    float acc = 0.f;
    for (int base = s; base < en; base += 64) {
        const int cnt = min(64, en - base);
        if (threadIdx.x < cnt) {
            const int e = edge_idx[base + threadIdx.x];
            ae[threadIdx.x]   = a_out[e];
            asrc[threadIdx.x] = src[e];
        }
        __syncthreads();
        for (int j = 0; j < cnt; ++j)
            acc += ae[j] * bf2f(qkv[(size_t)asrc[j] * NQKV + 512 + col]);
        __syncthreads();
    }
    out[(size_t)node * DIM + col] = acc;
}

// ---------------------------------------------------------------------------
extern "C" void kernel_launch(void* const* d_in, const int* in_sizes, int n_in,
                              void* d_out, int out_size, void* d_ws, size_t ws_size,
                              hipStream_t stream)
{
    const float* h      = (const float*)d_in[0];
    const int*   src    = (const int*)d_in[1];
    const int*   dst    = (const int*)d_in[2];
    const float* attn_q = (const float*)d_in[3];
    const float* attn_k = (const float*)d_in[4];
    const float* W      = (const float*)d_in[5];
    const float* bias   = (const float*)d_in[6];

    const int N = in_sizes[0] / DIM;
    const int E = in_sizes[1];

    float* out   = (float*)d_out;
    float* a_out = out + (size_t)N * DIM;

    char* ws = (char*)d_ws;
    ushort* h_bf  = (ushort*)ws; ws += (size_t)N * DIM * 2;
    ushort* qkv   = (ushort*)ws; ws += (size_t)N * NQKV * 2;
    ushort* bt    = (ushort*)ws; ws += (size_t)NQKV * DIM * 2;
    float* a_raw  = (float*)ws;  ws += (size_t)E * 4;
    int* edge_idx = (int*)ws;    ws += (size_t)E * 4;
    int* deg      = (int*)ws;    ws += (size_t)N * 4;
    int* cursor   = (int*)ws;    ws += (size_t)N * 4;
    double* partials = (double*)ws; ws += (size_t)STAT_BLOCKS * 2 * 8;
    float* coef   = (float*)ws;  ws += 8;
    int* row_ptr  = (int*)ws;    ws += (size_t)(N + 1) * 4;

    hipMemsetAsync(deg,    0, (size_t)N * 4, stream);
    hipMemsetAsync(cursor, 0, (size_t)N * 4, stream);

    const int total8 = N * DIM / 8;
    conv_h<<<(total8 + 255) / 256, 256, 0, stream>>>(h, h_bf, total8);
    build_bt<<<NQKV, 256, 0, stream>>>(attn_q, attn_k, W, bt);

    dim3 gg((N + 127) / 128, NQKV / 128);
    gemm_qkv_mfma<<<gg, 256, 0, stream>>>(h_bf, bt, bias, qkv, N);

    edge_dot<<<STAT_BLOCKS, 256, 0, stream>>>(qkv, src, dst, a_raw, deg, partials, E);
    scan_rowptr<<<1, 1024, 0, stream>>>(deg, row_ptr, N, partials, coef, E);
    scatter_edges<<<(E + 255) / 256, 256, 0, stream>>>(dst, row_ptr, cursor, edge_idx, E);
    edge_softmax<<<(N + 3) / 4, 256, 0, stream>>>(a_raw, row_ptr, edge_idx, coef, a_out, N);
    aggregate<<<N, 256, 0, stream>>>(qkv, a_out, src, row_ptr, edge_idx, out, N);
}

// Round 6
// 485.400 us; speedup vs baseline: 11.3314x; 1.0480x over previous
//
#include <hip/hip_runtime.h>
#include <math.h>

#define DIM 256
#define NQKV 768
#define STAT_BLOCKS 2048

typedef float  f32x4 __attribute__((ext_vector_type(4)));
typedef short  bs8   __attribute__((ext_vector_type(8)));

__device__ __forceinline__ ushort f2bf(float f) {
    unsigned int u = __float_as_uint(f);
    u += 0x7fffu + ((u >> 16) & 1u);
    return (ushort)(u >> 16);
}
__device__ __forceinline__ float bf2f(ushort u) {
    return __uint_as_float(((unsigned int)u) << 16);
}

#define MFMA16(c, a, b) \
    asm("s_nop 1\n\tv_mfma_f32_16x16x32_bf16 %0, %1, %2, %0" : "+v"(c) : "v"(a), "v"(b))

// ---------------------------------------------------------------------------
// K0a: h (f32) -> h_bf (bf16), 8 elems/thread
// ---------------------------------------------------------------------------
__global__ __launch_bounds__(256) void conv_h(
    const float* __restrict__ h, ushort* __restrict__ h_bf, int total8)
{
    const int idx = blockIdx.x * 256 + threadIdx.x;
    if (idx >= total8) return;
    const float4* hp = (const float4*)(h + (size_t)idx * 8);
    float4 a = hp[0], b = hp[1];
    uint4 o;
    o.x = (unsigned)f2bf(a.x) | ((unsigned)f2bf(a.y) << 16);
    o.y = (unsigned)f2bf(a.z) | ((unsigned)f2bf(a.w) << 16);
    o.z = (unsigned)f2bf(b.x) | ((unsigned)f2bf(b.y) << 16);
    o.w = (unsigned)f2bf(b.z) | ((unsigned)f2bf(b.w) << 16);
    *(uint4*)(h_bf + (size_t)idx * 8) = o;
}

// ---------------------------------------------------------------------------
// K0b: build BmatT [768][256] bf16 combined weights (col-major per output col)
// ---------------------------------------------------------------------------
__global__ __launch_bounds__(256) void build_bt(
    const float* __restrict__ attn_q, const float* __restrict__ attn_k,
    const float* __restrict__ W, ushort* __restrict__ bt)
{
    const int n = blockIdx.x;
    const int k = threadIdx.x;
    float val;
    if (n < 256)      val = attn_q[(size_t)k * 256 + n];
    else if (n < 512) val = attn_k[(size_t)k * 256 + (n - 256)];
    else              val = W[(size_t)(n - 512) * 256 + k];
    bt[(size_t)n * 256 + k] = f2bf(val);
}

// ---------------------------------------------------------------------------
// K1: MFMA GEMM:  qkv[M][768] (bf16) = h_bf[M][256] @ BmatT^T  (+bias on v)
// ---------------------------------------------------------------------------
__global__ __launch_bounds__(256) void gemm_qkv_mfma(
    const ushort* __restrict__ h_bf, const ushort* __restrict__ bt,
    const float* __restrict__ bias, ushort* __restrict__ qkv, int M)
{
    __shared__ __align__(16) ushort As[128 * 40];
    __shared__ __align__(16) ushort Bs[128 * 40];

    const int bm = blockIdx.x * 128;
    const int bn = blockIdx.y * 128;
    const int t    = threadIdx.x;
    const int lane = t & 63;
    const int wid  = t >> 6;
    const int wm   = wid >> 1;
    const int wn   = wid & 1;
    const int fr   = lane & 15;
    const int ko   = (lane >> 4) * 8;

    f32x4 acc[4][4];
    #pragma unroll
    for (int i = 0; i < 4; ++i)
        #pragma unroll
        for (int j = 0; j < 4; ++j)
            acc[i][j] = (f32x4){0.f, 0.f, 0.f, 0.f};

    for (int k0 = 0; k0 < DIM; k0 += 32) {
        #pragma unroll
        for (int ii = 0; ii < 2; ++ii) {
            const int s   = t * 2 + ii;
            const int row = s >> 2;
            const int sl  = s & 3;
            int ga = bm + row; if (ga > M - 1) ga = M - 1;
            uint4 va = *(const uint4*)(h_bf + (size_t)ga * 256 + k0 + sl * 8);
            *(uint4*)(As + row * 40 + sl * 8) = va;
            uint4 vb = *(const uint4*)(bt + (size_t)(bn + row) * 256 + k0 + sl * 8);
            *(uint4*)(Bs + row * 40 + sl * 8) = vb;
        }
        __syncthreads();

        bs8 af[4], bf_[4];
        #pragma unroll
        for (int f = 0; f < 4; ++f) {
            af[f]  = *(const bs8*)(As + (wm * 64 + f * 16 + fr) * 40 + ko);
            bf_[f] = *(const bs8*)(Bs + (wn * 64 + f * 16 + fr) * 40 + ko);
        }
        #pragma unroll
        for (int fm = 0; fm < 4; ++fm)
            #pragma unroll
            for (int fn = 0; fn < 4; ++fn)
                MFMA16(acc[fm][fn], af[fm], bf_[fn]);

        __syncthreads();
    }

    asm volatile("s_nop 7\n\ts_nop 7\n\ts_nop 7" ::: );

    #pragma unroll
    for (int fm = 0; fm < 4; ++fm) {
        const int rowbase = bm + wm * 64 + fm * 16 + (lane >> 4) * 4;
        #pragma unroll
        for (int fn = 0; fn < 4; ++fn) {
            const int col = bn + wn * 64 + fn * 16 + fr;
            float bv = (col >= 512) ? bias[col - 512] : 0.f;
            #pragma unroll
            for (int r = 0; r < 4; ++r) {
                const int row = rowbase + r;
                if (row < M)
                    qkv[(size_t)row * NQKV + col] = f2bf(acc[fm][fn][r] + bv);
            }
        }
    }
}

// ---------------------------------------------------------------------------
// K2: per-dst degree count
// ---------------------------------------------------------------------------
__global__ __launch_bounds__(256) void deg_count(
    const int* __restrict__ dst, int* __restrict__ deg, int E)
{
    const int e = blockIdx.x * 256 + threadIdx.x;
    if (e < E) atomicAdd(&deg[dst[e]], 1);
}

// ---------------------------------------------------------------------------
// K3: single block shuffle-scan deg -> row_ptr
// ---------------------------------------------------------------------------
__global__ __launch_bounds__(1024) void scan_rowptr(
    const int* __restrict__ deg, int* __restrict__ row_ptr, int N)
{
    const int tid  = threadIdx.x;
    const int lane = tid & 63;
    const int wv   = tid >> 6;

    if (tid == 0) row_ptr[0] = 0;

    __shared__ int woff[17];
    __shared__ int carryS;
    if (tid == 0) carryS = 0;
    __syncthreads();

    for (int base = 0; base < N; base += 4096) {
        int x[4], pre[4];
        int run = 0;
        #pragma unroll
        for (int j = 0; j < 4; ++j) {
            const int i = base + tid * 4 + j;
            const int v = (i < N) ? deg[i] : 0;
            pre[j] = run; x[j] = v; run += v;
        }
        int incl = run;
        #pragma unroll
        for (int off = 1; off < 64; off <<= 1) {
            int y = __shfl_up(incl, off);
            if (lane >= off) incl += y;
        }
        const int wex = incl - run;
        if (lane == 63) woff[wv] = incl;
        __syncthreads();
        if (wv == 0) {
            int wtot = (lane < 16) ? woff[lane] : 0;
            int winc = wtot;
            #pragma unroll
            for (int off = 1; off < 16; off <<= 1) {
                int y = __shfl_up(winc, off);
                if (lane >= off) winc += y;
            }
            if (lane < 16) woff[lane] = winc - wtot;
            if (lane == 15) woff[16] = winc;
        }
        __syncthreads();
        const int basev = carryS + woff[wv] + wex;
        #pragma unroll
        for (int j = 0; j < 4; ++j) {
            const int i = base + tid * 4 + j;
            if (i < N) row_ptr[i + 1] = basev + pre[j] + x[j];
        }
        __syncthreads();
        if (tid == 0) carryS += woff[16];
        __syncthreads();
    }
}

// ---------------------------------------------------------------------------
// K4: scatter edges into CSR order; pack {src, dst, orig_e} per slot
// ---------------------------------------------------------------------------
__global__ __launch_bounds__(256) void scatter_edges(
    const int* __restrict__ src, const int* __restrict__ dst,
    const int* __restrict__ row_ptr, int* __restrict__ cursor,
    int4* __restrict__ edata, int E)
{
    const int e = blockIdx.x * 256 + threadIdx.x;
    if (e < E) {
        const int d = dst[e];
        const int pos = row_ptr[d] + atomicAdd(&cursor[d], 1);
        edata[pos] = make_int4(src[e], d, e, 0);
    }
}

// ---------------------------------------------------------------------------
// K5: per-edge raw score in CSR order.  Each wave owns a CONTIGUOUS chunk so
// the k[dst] row stays hot in L1 across its ~16 same-dst edges.  2-edge
// unroll for memory-level parallelism.  Stats partials per block.
// ---------------------------------------------------------------------------
__global__ __launch_bounds__(256) void edge_dot_csr(
    const ushort* __restrict__ qkv, const int4* __restrict__ edata,
    float* __restrict__ a_rawc, double* __restrict__ partials, int E)
{
    const int lane = threadIdx.x & 63;
    const int wid  = threadIdx.x >> 6;
    const int w    = blockIdx.x * 4 + wid;
    const int nw   = gridDim.x * 4;
    const int chunk = (E + nw - 1) / nw;
    const int p0 = w * chunk;
    const int p1 = min(E, p0 + chunk);

    double lsum = 0.0, lsum2 = 0.0;
    int p = p0;
    for (; p + 2 <= p1; p += 2) {
        const int4 e0 = edata[p];
        const int4 e1 = edata[p + 1];
        ushort4 qa0 = *(const ushort4*)(qkv + (size_t)e0.x * NQKV + lane * 4);
        ushort4 kb0 = *(const ushort4*)(qkv + (size_t)e0.y * NQKV + 256 + lane * 4);
        ushort4 qa1 = *(const ushort4*)(qkv + (size_t)e1.x * NQKV + lane * 4);
        ushort4 kb1 = *(const ushort4*)(qkv + (size_t)e1.y * NQKV + 256 + lane * 4);
        float d0 = bf2f(qa0.x) * bf2f(kb0.x) + bf2f(qa0.y) * bf2f(kb0.y)
                 + bf2f(qa0.z) * bf2f(kb0.z) + bf2f(qa0.w) * bf2f(kb0.w);
        float d1 = bf2f(qa1.x) * bf2f(kb1.x) + bf2f(qa1.y) * bf2f(kb1.y)
                 + bf2f(qa1.z) * bf2f(kb1.z) + bf2f(qa1.w) * bf2f(kb1.w);
        #pragma unroll
        for (int off = 32; off; off >>= 1) {
            d0 += __shfl_xor(d0, off);
            d1 += __shfl_xor(d1, off);
        }
        if (lane == 0) {
            a_rawc[p]     = d0;
            a_rawc[p + 1] = d1;
            lsum  += (double)d0 + (double)d1;
            lsum2 += (double)d0 * (double)d0 + (double)d1 * (double)d1;
        }
    }
    if (p < p1) {
        const int4 e0 = edata[p];
        ushort4 qa0 = *(const ushort4*)(qkv + (size_t)e0.x * NQKV + lane * 4);
        ushort4 kb0 = *(const ushort4*)(qkv + (size_t)e0.y * NQKV + 256 + lane * 4);
        float d0 = bf2f(qa0.x) * bf2f(kb0.x) + bf2f(qa0.y) * bf2f(kb0.y)
                 + bf2f(qa0.z) * bf2f(kb0.z) + bf2f(qa0.w) * bf2f(kb0.w);
        #pragma unroll
        for (int off = 32; off; off >>= 1) d0 += __shfl_xor(d0, off);
        if (lane == 0) {
            a_rawc[p] = d0;
            lsum  += (double)d0;
            lsum2 += (double)d0 * (double)d0;
        }
    }

    __shared__ double bsum[4], bsum2[4];
    if (lane == 0) { bsum[wid] = lsum; bsum2[wid] = lsum2; }
    __syncthreads();
    if (threadIdx.x == 0) {
        partials[blockIdx.x]             = bsum[0] + bsum[1] + bsum[2] + bsum[3];
        partials[gridDim.x + blockIdx.x] = bsum2[0] + bsum2[1] + bsum2[2] + bsum2[3];
    }
}

// ---------------------------------------------------------------------------
// K6: reduce stat partials -> coef {mean, 1/(std*T)}
// ---------------------------------------------------------------------------
__global__ __launch_bounds__(256) void finalize_coef(
    const double* __restrict__ partials, float* __restrict__ coef, int E)
{
    __shared__ double red[256];
    const int tid = threadIdx.x;
    double s1 = 0.0, s2 = 0.0;
    for (int i = tid; i < STAT_BLOCKS; i += 256) {
        s1 += partials[i];
        s2 += partials[STAT_BLOCKS + i];
    }
    red[tid] = s1;
    __syncthreads();
    for (int off = 128; off; off >>= 1) {
        if (tid < off) red[tid] += red[tid + off];
        __syncthreads();
    }
    const double tot1 = red[0];
    __syncthreads();
    red[tid] = s2;
    __syncthreads();
    for (int off = 128; off; off >>= 1) {
        if (tid < off) red[tid] += red[tid + off];
        __syncthreads();
    }
    if (tid == 0) {
        const double mean = tot1 / (double)E;
        const double var  = red[0] / (double)E - mean * mean;
        coef[0] = (float)mean;
        coef[1] = (float)(1.0 / (sqrt(var) * 0.5));   // /std /TEMPERATURE
    }
}

// ---------------------------------------------------------------------------
// K7: fused per-node softmax + aggregation.
// Scores are standardized (|x| small) -> skip max subtraction (fp32-safe).
// phase 1: sum of exp over contiguous scores.  phase 2: weights -> a_out
// (scattered to original edge order) and weighted v-gather into out.
// ---------------------------------------------------------------------------
__global__ __launch_bounds__(256) void agg_fused(
    const ushort* __restrict__ qkv, const float* __restrict__ a_rawc,
    const int4* __restrict__ edata, const int* __restrict__ row_ptr,
    const float* __restrict__ coef,
    float* __restrict__ out, float* __restrict__ a_out, int N)
{
    const int node = blockIdx.x;
    const int tid  = threadIdx.x;
    const int lane = tid & 63;
    const int wv   = tid >> 6;
    const int s  = row_ptr[node];
    const int en = row_ptr[node + 1];
    const float mean = coef[0];
    const float mul  = coef[1];

    // ---- phase 1: sum of exp ----
    float lsum = 0.f;
    for (int j = s + tid; j < en; j += 256)
        lsum += __expf((a_rawc[j] - mean) * mul);
    #pragma unroll
    for (int off = 32; off; off >>= 1) lsum += __shfl_xor(lsum, off);
    __shared__ float ws4[4];
    if (lane == 0) ws4[wv] = lsum;
    __syncthreads();
    const float rcp = 1.0f / (ws4[0] + ws4[1] + ws4[2] + ws4[3]);

    // ---- phase 2: weights + gather ----
    __shared__ float ae[64];
    __shared__ int   asrc[64];
    float acc = 0.f;
    for (int base = s; base < en; base += 64) {
        const int cnt = min(64, en - base);
        __syncthreads();
        if (tid < cnt) {
            const int4 ed = edata[base + tid];
            const float wgt = __expf((a_rawc[base + tid] - mean) * mul) * rcp;
            ae[tid]   = wgt;
            asrc[tid] = ed.x;
            a_out[ed.z] = wgt;
        }
        __syncthreads();
        #pragma unroll 4
        for (int j = 0; j < cnt; ++j)
            acc += ae[j] * bf2f(qkv[(size_t)asrc[j] * NQKV + 512 + tid]);
    }
    out[(size_t)node * DIM + tid] = acc;
}

// ---------------------------------------------------------------------------
extern "C" void kernel_launch(void* const* d_in, const int* in_sizes, int n_in,
                              void* d_out, int out_size, void* d_ws, size_t ws_size,
                              hipStream_t stream)
{
    const float* h      = (const float*)d_in[0];
    const int*   src    = (const int*)d_in[1];
    const int*   dst    = (const int*)d_in[2];
    const float* attn_q = (const float*)d_in[3];
    const float* attn_k = (const float*)d_in[4];
    const float* W      = (const float*)d_in[5];
    const float* bias   = (const float*)d_in[6];

    const int N = in_sizes[0] / DIM;
    const int E = in_sizes[1];

    float* out   = (float*)d_out;
    float* a_out = out + (size_t)N * DIM;

    char* ws = (char*)d_ws;
    ushort* h_bf  = (ushort*)ws;
    int4*   edata = (int4*)ws;               // ALIAS: reuses h_bf after gemm
    ws += (size_t)N * DIM * 2;               // 25.6 MB (edata needs 12.8 MB)
    ushort* qkv   = (ushort*)ws; ws += (size_t)N * NQKV * 2;
    ushort* bt    = (ushort*)ws; ws += (size_t)NQKV * DIM * 2;
    float* a_rawc = (float*)ws;  ws += (size_t)E * 4;
    int* deg      = (int*)ws;    ws += (size_t)N * 4;
    int* cursor   = (int*)ws;    ws += (size_t)N * 4;
    double* partials = (double*)ws; ws += (size_t)STAT_BLOCKS * 2 * 8;
    float* coef   = (float*)ws;  ws += 8;
    int* row_ptr  = (int*)ws;    ws += (size_t)(N + 1) * 4;

    hipMemsetAsync(deg,    0, (size_t)N * 4, stream);
    hipMemsetAsync(cursor, 0, (size_t)N * 4, stream);

    const int total8 = N * DIM / 8;
    conv_h<<<(total8 + 255) / 256, 256, 0, stream>>>(h, h_bf, total8);
    build_bt<<<NQKV, 256, 0, stream>>>(attn_q, attn_k, W, bt);

    dim3 gg((N + 127) / 128, NQKV / 128);
    gemm_qkv_mfma<<<gg, 256, 0, stream>>>(h_bf, bt, bias, qkv, N);

    deg_count<<<(E + 255) / 256, 256, 0, stream>>>(dst, deg, E);
    scan_rowptr<<<1, 1024, 0, stream>>>(deg, row_ptr, N);
    scatter_edges<<<(E + 255) / 256, 256, 0, stream>>>(src, dst, row_ptr, cursor, edata, E);
    edge_dot_csr<<<STAT_BLOCKS, 256, 0, stream>>>(qkv, edata, a_rawc, partials, E);
    finalize_coef<<<1, 256, 0, stream>>>(partials, coef, E);
    agg_fused<<<N, 256, 0, stream>>>(qkv, a_rawc, edata, row_ptr, coef, out, a_out, N);
}

// Round 7
// 461.858 us; speedup vs baseline: 11.9090x; 1.0510x over previous
//
#include <hip/hip_runtime.h>
#include <math.h>

#define DIM 256
#define NQKV 768
#define STAT_BLOCKS 2048

typedef float  f32x4 __attribute__((ext_vector_type(4)));
typedef short  bs8   __attribute__((ext_vector_type(8)));

__device__ __forceinline__ ushort f2bf(float f) {
    unsigned int u = __float_as_uint(f);
    u += 0x7fffu + ((u >> 16) & 1u);
    return (ushort)(u >> 16);
}
__device__ __forceinline__ float bf2f(ushort u) {
    return __uint_as_float(((unsigned int)u) << 16);
}
// dot of 8 bf16 pairs packed in uint4 (fp32 accumulate)
__device__ __forceinline__ float dotu4(uint4 a, uint4 b) {
    float s;
    s  = bf2f((ushort)a.x) * bf2f((ushort)b.x) + bf2f((ushort)(a.x >> 16)) * bf2f((ushort)(b.x >> 16));
    s += bf2f((ushort)a.y) * bf2f((ushort)b.y) + bf2f((ushort)(a.y >> 16)) * bf2f((ushort)(b.y >> 16));
    s += bf2f((ushort)a.z) * bf2f((ushort)b.z) + bf2f((ushort)(a.z >> 16)) * bf2f((ushort)(b.z >> 16));
    s += bf2f((ushort)a.w) * bf2f((ushort)b.w) + bf2f((ushort)(a.w >> 16)) * bf2f((ushort)(b.w >> 16));
    return s;
}

#define MFMA16(c, a, b) \
    asm("s_nop 1\n\tv_mfma_f32_16x16x32_bf16 %0, %1, %2, %0" : "+v"(c) : "v"(a), "v"(b))

// ---------------------------------------------------------------------------
// K0a: h (f32) -> h_bf (bf16), 8 elems/thread
// ---------------------------------------------------------------------------
__global__ __launch_bounds__(256) void conv_h(
    const float* __restrict__ h, ushort* __restrict__ h_bf, int total8)
{
    const int idx = blockIdx.x * 256 + threadIdx.x;
    if (idx >= total8) return;
    const float4* hp = (const float4*)(h + (size_t)idx * 8);
    float4 a = hp[0], b = hp[1];
    uint4 o;
    o.x = (unsigned)f2bf(a.x) | ((unsigned)f2bf(a.y) << 16);
    o.y = (unsigned)f2bf(a.z) | ((unsigned)f2bf(a.w) << 16);
    o.z = (unsigned)f2bf(b.x) | ((unsigned)f2bf(b.y) << 16);
    o.w = (unsigned)f2bf(b.z) | ((unsigned)f2bf(b.w) << 16);
    *(uint4*)(h_bf + (size_t)idx * 8) = o;
}

// ---------------------------------------------------------------------------
// K0b: build BmatT [768][256] bf16 combined weights
// ---------------------------------------------------------------------------
__global__ __launch_bounds__(256) void build_bt(
    const float* __restrict__ attn_q, const float* __restrict__ attn_k,
    const float* __restrict__ W, ushort* __restrict__ bt)
{
    const int n = blockIdx.x;
    const int k = threadIdx.x;
    float val;
    if (n < 256)      val = attn_q[(size_t)k * 256 + n];
    else if (n < 512) val = attn_k[(size_t)k * 256 + (n - 256)];
    else              val = W[(size_t)(n - 512) * 256 + k];
    bt[(size_t)n * 256 + k] = f2bf(val);
}

// ---------------------------------------------------------------------------
// K1: MFMA GEMM:  qkv[M][768] (bf16) = h_bf[M][256] @ BmatT^T  (+bias on v)
// ---------------------------------------------------------------------------
__global__ __launch_bounds__(256) void gemm_qkv_mfma(
    const ushort* __restrict__ h_bf, const ushort* __restrict__ bt,
    const float* __restrict__ bias, ushort* __restrict__ qkv, int M)
{
    __shared__ __align__(16) ushort As[128 * 40];
    __shared__ __align__(16) ushort Bs[128 * 40];

    const int bm = blockIdx.x * 128;
    const int bn = blockIdx.y * 128;
    const int t    = threadIdx.x;
    const int lane = t & 63;
    const int wid  = t >> 6;
    const int wm   = wid >> 1;
    const int wn   = wid & 1;
    const int fr   = lane & 15;
    const int ko   = (lane >> 4) * 8;

    f32x4 acc[4][4];
    #pragma unroll
    for (int i = 0; i < 4; ++i)
        #pragma unroll
        for (int j = 0; j < 4; ++j)
            acc[i][j] = (f32x4){0.f, 0.f, 0.f, 0.f};

    for (int k0 = 0; k0 < DIM; k0 += 32) {
        #pragma unroll
        for (int ii = 0; ii < 2; ++ii) {
            const int s   = t * 2 + ii;
            const int row = s >> 2;
            const int sl  = s & 3;
            int ga = bm + row; if (ga > M - 1) ga = M - 1;
            uint4 va = *(const uint4*)(h_bf + (size_t)ga * 256 + k0 + sl * 8);
            *(uint4*)(As + row * 40 + sl * 8) = va;
            uint4 vb = *(const uint4*)(bt + (size_t)(bn + row) * 256 + k0 + sl * 8);
            *(uint4*)(Bs + row * 40 + sl * 8) = vb;
        }
        __syncthreads();

        bs8 af[4], bf_[4];
        #pragma unroll
        for (int f = 0; f < 4; ++f) {
            af[f]  = *(const bs8*)(As + (wm * 64 + f * 16 + fr) * 40 + ko);
            bf_[f] = *(const bs8*)(Bs + (wn * 64 + f * 16 + fr) * 40 + ko);
        }
        #pragma unroll
        for (int fm = 0; fm < 4; ++fm)
            #pragma unroll
            for (int fn = 0; fn < 4; ++fn)
                MFMA16(acc[fm][fn], af[fm], bf_[fn]);

        __syncthreads();
    }

    asm volatile("s_nop 7\n\ts_nop 7\n\ts_nop 7" ::: );

    #pragma unroll
    for (int fm = 0; fm < 4; ++fm) {
        const int rowbase = bm + wm * 64 + fm * 16 + (lane >> 4) * 4;
        #pragma unroll
        for (int fn = 0; fn < 4; ++fn) {
            const int col = bn + wn * 64 + fn * 16 + fr;
            float bv = (col >= 512) ? bias[col - 512] : 0.f;
            #pragma unroll
            for (int r = 0; r < 4; ++r) {
                const int row = rowbase + r;
                if (row < M)
                    qkv[(size_t)row * NQKV + col] = f2bf(acc[fm][fn][r] + bv);
            }
        }
    }
}

// ---------------------------------------------------------------------------
// K2: per-dst degree count
// ---------------------------------------------------------------------------
__global__ __launch_bounds__(256) void deg_count(
    const int* __restrict__ dst, int* __restrict__ deg, int E)
{
    const int e = blockIdx.x * 256 + threadIdx.x;
    if (e < E) atomicAdd(&deg[dst[e]], 1);
}

// ---------------------------------------------------------------------------
// K3: single block shuffle-scan deg -> row_ptr
// ---------------------------------------------------------------------------
__global__ __launch_bounds__(1024) void scan_rowptr(
    const int* __restrict__ deg, int* __restrict__ row_ptr, int N)
{
    const int tid  = threadIdx.x;
    const int lane = tid & 63;
    const int wv   = tid >> 6;

    if (tid == 0) row_ptr[0] = 0;

    __shared__ int woff[17];
    __shared__ int carryS;
    if (tid == 0) carryS = 0;
    __syncthreads();

    for (int base = 0; base < N; base += 4096) {
        int x[4], pre[4];
        int run = 0;
        #pragma unroll
        for (int j = 0; j < 4; ++j) {
            const int i = base + tid * 4 + j;
            const int v = (i < N) ? deg[i] : 0;
            pre[j] = run; x[j] = v; run += v;
        }
        int incl = run;
        #pragma unroll
        for (int off = 1; off < 64; off <<= 1) {
            int y = __shfl_up(incl, off);
            if (lane >= off) incl += y;
        }
        const int wex = incl - run;
        if (lane == 63) woff[wv] = incl;
        __syncthreads();
        if (wv == 0) {
            int wtot = (lane < 16) ? woff[lane] : 0;
            int winc = wtot;
            #pragma unroll
            for (int off = 1; off < 16; off <<= 1) {
                int y = __shfl_up(winc, off);
                if (lane >= off) winc += y;
            }
            if (lane < 16) woff[lane] = winc - wtot;
            if (lane == 15) woff[16] = winc;
        }
        __syncthreads();
        const int basev = carryS + woff[wv] + wex;
        #pragma unroll
        for (int j = 0; j < 4; ++j) {
            const int i = base + tid * 4 + j;
            if (i < N) row_ptr[i + 1] = basev + pre[j] + x[j];
        }
        __syncthreads();
        if (tid == 0) carryS += woff[16];
        __syncthreads();
    }
}

// ---------------------------------------------------------------------------
// K4: scatter edges into CSR order; pack {src, dst, orig_e}
// ---------------------------------------------------------------------------
__global__ __launch_bounds__(256) void scatter_edges(
    const int* __restrict__ src, const int* __restrict__ dst,
    const int* __restrict__ row_ptr, int* __restrict__ cursor,
    int4* __restrict__ edata, int E)
{
    const int e = blockIdx.x * 256 + threadIdx.x;
    if (e < E) {
        const int d = dst[e];
        const int pos = row_ptr[d] + atomicAdd(&cursor[d], 1);
        edata[pos] = make_int4(src[e], d, e, 0);
    }
}

// ---------------------------------------------------------------------------
// K5: per-edge raw score in CSR order.  Half-wave (32 lanes, uint4=16B/lane)
// per edge; 8 edges per iteration -> 4 q + 4 k loads in flight per lane.
// ---------------------------------------------------------------------------
__global__ __launch_bounds__(256) void edge_dot_csr(
    const ushort* __restrict__ qkv, const int4* __restrict__ edata,
    float* __restrict__ a_rawc, double* __restrict__ partials, int E)
{
    const int lane = threadIdx.x & 63;
    const int wid  = threadIdx.x >> 6;
    const int lq   = lane & 31;        // lane within half-wave
    const int hh   = lane >> 5;        // half-wave id (0/1)
    const int w    = blockIdx.x * 4 + wid;
    const int nw   = gridDim.x * 4;
    const int chunk = (E + nw - 1) / nw;
    const int p0 = min(E, w * chunk);
    const int p1 = min(E, p0 + chunk);

    double lsum = 0.0, lsum2 = 0.0;
    int p = p0;

    for (; p + 8 <= p1; p += 8) {
        const int4 ed0 = edata[p     + hh];
        const int4 ed1 = edata[p + 2 + hh];
        const int4 ed2 = edata[p + 4 + hh];
        const int4 ed3 = edata[p + 6 + hh];
        uint4 q0 = *(const uint4*)(qkv + (size_t)ed0.x * NQKV + lq * 8);
        uint4 q1 = *(const uint4*)(qkv + (size_t)ed1.x * NQKV + lq * 8);
        uint4 q2 = *(const uint4*)(qkv + (size_t)ed2.x * NQKV + lq * 8);
        uint4 q3 = *(const uint4*)(qkv + (size_t)ed3.x * NQKV + lq * 8);
        uint4 k0 = *(const uint4*)(qkv + (size_t)ed0.y * NQKV + 256 + lq * 8);
        uint4 k1 = *(const uint4*)(qkv + (size_t)ed1.y * NQKV + 256 + lq * 8);
        uint4 k2 = *(const uint4*)(qkv + (size_t)ed2.y * NQKV + 256 + lq * 8);
        uint4 k3 = *(const uint4*)(qkv + (size_t)ed3.y * NQKV + 256 + lq * 8);
        float d0 = dotu4(q0, k0);
        float d1 = dotu4(q1, k1);
        float d2 = dotu4(q2, k2);
        float d3 = dotu4(q3, k3);
        #pragma unroll
        for (int off = 16; off; off >>= 1) {
            d0 += __shfl_xor(d0, off);
            d1 += __shfl_xor(d1, off);
            d2 += __shfl_xor(d2, off);
            d3 += __shfl_xor(d3, off);
        }
        if (lq == 0) {
            a_rawc[p     + hh] = d0;
            a_rawc[p + 2 + hh] = d1;
            a_rawc[p + 4 + hh] = d2;
            a_rawc[p + 6 + hh] = d3;
            lsum  += (double)d0 + (double)d1 + (double)d2 + (double)d3;
            lsum2 += (double)d0 * d0 + (double)d1 * d1
                   + (double)d2 * d2 + (double)d3 * d3;
        }
    }
    for (; p + 2 <= p1; p += 2) {
        const int4 ed0 = edata[p + hh];
        uint4 q0 = *(const uint4*)(qkv + (size_t)ed0.x * NQKV + lq * 8);
        uint4 k0 = *(const uint4*)(qkv + (size_t)ed0.y * NQKV + 256 + lq * 8);
        float d0 = dotu4(q0, k0);
        #pragma unroll
        for (int off = 16; off; off >>= 1) d0 += __shfl_xor(d0, off);
        if (lq == 0) {
            a_rawc[p + hh] = d0;
            lsum  += (double)d0;
            lsum2 += (double)d0 * d0;
        }
    }
    if (p < p1) {   // single tail edge: both half-waves load it, half 0 writes
        const int4 ed0 = edata[p];
        uint4 q0 = *(const uint4*)(qkv + (size_t)ed0.x * NQKV + lq * 8);
        uint4 k0 = *(const uint4*)(qkv + (size_t)ed0.y * NQKV + 256 + lq * 8);
        float d0 = dotu4(q0, k0);
        #pragma unroll
        for (int off = 16; off; off >>= 1) d0 += __shfl_xor(d0, off);
        if (lane == 0) {
            a_rawc[p] = d0;
            lsum  += (double)d0;
            lsum2 += (double)d0 * d0;
        }
    }

    // combine the two half-wave accumulators (lanes 0 and 32) onto lane 0
    lsum  += __shfl_xor(lsum, 32);
    lsum2 += __shfl_xor(lsum2, 32);

    __shared__ double bsum[4], bsum2[4];
    if (lane == 0) { bsum[wid] = lsum; bsum2[wid] = lsum2; }
    __syncthreads();
    if (threadIdx.x == 0) {
        partials[blockIdx.x]             = bsum[0] + bsum[1] + bsum[2] + bsum[3];
        partials[gridDim.x + blockIdx.x] = bsum2[0] + bsum2[1] + bsum2[2] + bsum2[3];
    }
}

// ---------------------------------------------------------------------------
// K6: reduce stat partials -> coef {mean, 1/(std*T)}
// ---------------------------------------------------------------------------
__global__ __launch_bounds__(256) void finalize_coef(
    const double* __restrict__ partials, float* __restrict__ coef, int E)
{
    __shared__ double red[256];
    const int tid = threadIdx.x;
    double s1 = 0.0, s2 = 0.0;
    for (int i = tid; i < STAT_BLOCKS; i += 256) {
        s1 += partials[i];
        s2 += partials[STAT_BLOCKS + i];
    }
    red[tid] = s1;
    __syncthreads();
    for (int off = 128; off; off >>= 1) {
        if (tid < off) red[tid] += red[tid + off];
        __syncthreads();
    }
    const double tot1 = red[0];
    __syncthreads();
    red[tid] = s2;
    __syncthreads();
    for (int off = 128; off; off >>= 1) {
        if (tid < off) red[tid] += red[tid + off];
        __syncthreads();
    }
    if (tid == 0) {
        const double mean = tot1 / (double)E;
        const double var  = red[0] / (double)E - mean * mean;
        coef[0] = (float)mean;
        coef[1] = (float)(1.0 / (sqrt(var) * 0.5));   // /std /TEMPERATURE
    }
}

// ---------------------------------------------------------------------------
// K7: fused per-node softmax + aggregation.  Wave-per-edge (4 streams/block),
// lane covers 4 cols (ushort4), 2-deep unroll; cross-wave combine in LDS.
// ---------------------------------------------------------------------------
__global__ __launch_bounds__(256) void agg_fused(
    const ushort* __restrict__ qkv, const float* __restrict__ a_rawc,
    const int4* __restrict__ edata, const int* __restrict__ row_ptr,
    const float* __restrict__ coef,
    float* __restrict__ out, float* __restrict__ a_out, int N)
{
    const int node = blockIdx.x;
    const int tid  = threadIdx.x;
    const int lane = tid & 63;
    const int wv   = tid >> 6;
    const int s  = row_ptr[node];
    const int en = row_ptr[node + 1];
    const float mean = coef[0];
    const float mul  = coef[1];

    // ---- phase 1: sum of exp (scores contiguous; skip max: |x| bounded) ----
    float lsum = 0.f;
    for (int j = s + tid; j < en; j += 256)
        lsum += __expf((a_rawc[j] - mean) * mul);
    #pragma unroll
    for (int off = 32; off; off >>= 1) lsum += __shfl_xor(lsum, off);
    __shared__ float ws4[4];
    if (lane == 0) ws4[wv] = lsum;
    __syncthreads();
    const float rcp = 1.0f / (ws4[0] + ws4[1] + ws4[2] + ws4[3]);

    // ---- phase 2: wave-per-edge weighted v-gather ----
    float4 acc = make_float4(0.f, 0.f, 0.f, 0.f);
    int j = s + wv;
    for (; j + 4 < en; j += 8) {
        const int4 edA = edata[j];
        const int4 edB = edata[j + 4];
        const float wA = __expf((a_rawc[j]     - mean) * mul) * rcp;
        const float wB = __expf((a_rawc[j + 4] - mean) * mul) * rcp;
        ushort4 vA = *(const ushort4*)(qkv + (size_t)edA.x * NQKV + 512 + lane * 4);
        ushort4 vB = *(const ushort4*)(qkv + (size_t)edB.x * NQKV + 512 + lane * 4);
        if (lane == 0) { a_out[edA.z] = wA; a_out[edB.z] = wB; }
        acc.x += wA * bf2f(vA.x) + wB * bf2f(vB.x);
        acc.y += wA * bf2f(vA.y) + wB * bf2f(vB.y);
        acc.z += wA * bf2f(vA.z) + wB * bf2f(vB.z);
        acc.w += wA * bf2f(vA.w) + wB * bf2f(vB.w);
    }
    if (j < en) {
        const int4 edA = edata[j];
        const float wA = __expf((a_rawc[j] - mean) * mul) * rcp;
        ushort4 vA = *(const ushort4*)(qkv + (size_t)edA.x * NQKV + 512 + lane * 4);
        if (lane == 0) a_out[edA.z] = wA;
        acc.x += wA * bf2f(vA.x);
        acc.y += wA * bf2f(vA.y);
        acc.z += wA * bf2f(vA.z);
        acc.w += wA * bf2f(vA.w);
    }

    __shared__ float lds[4][DIM];
    *(float4*)&lds[wv][lane * 4] = acc;
    __syncthreads();
    out[(size_t)node * DIM + tid] =
        lds[0][tid] + lds[1][tid] + lds[2][tid] + lds[3][tid];
}

// ---------------------------------------------------------------------------
extern "C" void kernel_launch(void* const* d_in, const int* in_sizes, int n_in,
                              void* d_out, int out_size, void* d_ws, size_t ws_size,
                              hipStream_t stream)
{
    const float* h      = (const float*)d_in[0];
    const int*   src    = (const int*)d_in[1];
    const int*   dst    = (const int*)d_in[2];
    const float* attn_q = (const float*)d_in[3];
    const float* attn_k = (const float*)d_in[4];
    const float* W      = (const float*)d_in[5];
    const float* bias   = (const float*)d_in[6];

    const int N = in_sizes[0] / DIM;
    const int E = in_sizes[1];

    float* out   = (float*)d_out;
    float* a_out = out + (size_t)N * DIM;

    char* ws = (char*)d_ws;
    ushort* h_bf  = (ushort*)ws;
    int4*   edata = (int4*)ws;               // ALIAS: reuses h_bf after gemm
    ws += (size_t)N * DIM * 2;               // 25.6 MB (edata needs 12.8 MB)
    ushort* qkv   = (ushort*)ws; ws += (size_t)N * NQKV * 2;
    ushort* bt    = (ushort*)ws; ws += (size_t)NQKV * DIM * 2;
    float* a_rawc = (float*)ws;  ws += (size_t)E * 4;
    int* deg      = (int*)ws;    ws += (size_t)N * 4;
    int* cursor   = (int*)ws;    ws += (size_t)N * 4;
    double* partials = (double*)ws; ws += (size_t)STAT_BLOCKS * 2 * 8;
    float* coef   = (float*)ws;  ws += 8;
    int* row_ptr  = (int*)ws;    ws += (size_t)(N + 1) * 4;

    hipMemsetAsync(deg,    0, (size_t)N * 4, stream);
    hipMemsetAsync(cursor, 0, (size_t)N * 4, stream);

    const int total8 = N * DIM / 8;
    conv_h<<<(total8 + 255) / 256, 256, 0, stream>>>(h, h_bf, total8);
    build_bt<<<NQKV, 256, 0, stream>>>(attn_q, attn_k, W, bt);

    dim3 gg((N + 127) / 128, NQKV / 128);
    gemm_qkv_mfma<<<gg, 256, 0, stream>>>(h_bf, bt, bias, qkv, N);

    deg_count<<<(E + 255) / 256, 256, 0, stream>>>(dst, deg, E);
    scan_rowptr<<<1, 1024, 0, stream>>>(deg, row_ptr, N);
    scatter_edges<<<(E + 255) / 256, 256, 0, stream>>>(src, dst, row_ptr, cursor, edata, E);
    edge_dot_csr<<<STAT_BLOCKS, 256, 0, stream>>>(qkv, edata, a_rawc, partials, E);
    finalize_coef<<<1, 256, 0, stream>>>(partials, coef, E);
    agg_fused<<<N, 256, 0, stream>>>(qkv, a_rawc, edata, row_ptr, coef, out, a_out, N);
}

// Round 8
// 422.301 us; speedup vs baseline: 13.0245x; 1.0937x over previous
//
#include <hip/hip_runtime.h>
#include <math.h>

#define DIM 256
#define NQKV 768
#define STAT_BLOCKS 2048

typedef float  f32x4 __attribute__((ext_vector_type(4)));
typedef short  bs8   __attribute__((ext_vector_type(8)));

__device__ __forceinline__ ushort f2bf(float f) {
    unsigned int u = __float_as_uint(f);
    u += 0x7fffu + ((u >> 16) & 1u);
    return (ushort)(u >> 16);
}
__device__ __forceinline__ float bf2f(ushort u) {
    return __uint_as_float(((unsigned int)u) << 16);
}
// dot of 8 bf16 pairs packed in uint4 (fp32 accumulate)
__device__ __forceinline__ float dotu4(uint4 a, uint4 b) {
    float s;
    s  = bf2f((ushort)a.x) * bf2f((ushort)b.x) + bf2f((ushort)(a.x >> 16)) * bf2f((ushort)(b.x >> 16));
    s += bf2f((ushort)a.y) * bf2f((ushort)b.y) + bf2f((ushort)(a.y >> 16)) * bf2f((ushort)(b.y >> 16));
    s += bf2f((ushort)a.z) * bf2f((ushort)b.z) + bf2f((ushort)(a.z >> 16)) * bf2f((ushort)(b.z >> 16));
    s += bf2f((ushort)a.w) * bf2f((ushort)b.w) + bf2f((ushort)(a.w >> 16)) * bf2f((ushort)(b.w >> 16));
    return s;
}

#define MFMA16(c, a, b) \
    asm("s_nop 1\n\tv_mfma_f32_16x16x32_bf16 %0, %1, %2, %0" : "+v"(c) : "v"(a), "v"(b))

// global -> LDS DMA, 16B per lane; LDS dest is wave-uniform base + lane*16
#define GLOAD_LDS16(g, l) __builtin_amdgcn_global_load_lds( \
    (const __attribute__((address_space(1))) unsigned int*)(g), \
    (__attribute__((address_space(3))) unsigned int*)(l), 16, 0, 0)

// ---------------------------------------------------------------------------
// K0a: h (f32) -> h_bf (bf16), 8 elems/thread
// ---------------------------------------------------------------------------
__global__ __launch_bounds__(256) void conv_h(
    const float* __restrict__ h, ushort* __restrict__ h_bf, int total8)
{
    const int idx = blockIdx.x * 256 + threadIdx.x;
    if (idx >= total8) return;
    const float4* hp = (const float4*)(h + (size_t)idx * 8);
    float4 a = hp[0], b = hp[1];
    uint4 o;
    o.x = (unsigned)f2bf(a.x) | ((unsigned)f2bf(a.y) << 16);
    o.y = (unsigned)f2bf(a.z) | ((unsigned)f2bf(a.w) << 16);
    o.z = (unsigned)f2bf(b.x) | ((unsigned)f2bf(b.y) << 16);
    o.w = (unsigned)f2bf(b.z) | ((unsigned)f2bf(b.w) << 16);
    *(uint4*)(h_bf + (size_t)idx * 8) = o;
}

// ---------------------------------------------------------------------------
// K0b: build BmatT [768][256] bf16 combined weights
// ---------------------------------------------------------------------------
__global__ __launch_bounds__(256) void build_bt(
    const float* __restrict__ attn_q, const float* __restrict__ attn_k,
    const float* __restrict__ W, ushort* __restrict__ bt)
{
    const int n = blockIdx.x;
    const int k = threadIdx.x;
    float val;
    if (n < 256)      val = attn_q[(size_t)k * 256 + n];
    else if (n < 512) val = attn_k[(size_t)k * 256 + (n - 256)];
    else              val = W[(size_t)(n - 512) * 256 + k];
    bt[(size_t)n * 256 + k] = f2bf(val);
}

// ---------------------------------------------------------------------------
// K1: MFMA GEMM:  qkv[M][768] (bf16) = h_bf[M][256] @ BmatT^T  (+bias on v)
// 128x128 tile, 4 waves (2x2), K-step 32.
// Staging via global_load_lds (16B/lane) into LINEAR 64B LDS rows; bank
// spreading via chunk-XOR applied on the pre-swizzled GLOBAL source:
//   LDS(row, c) holds global chunk (c ^ (row&3)); ds_read uses the same XOR.
// ---------------------------------------------------------------------------
__global__ __launch_bounds__(256) void gemm_qkv_mfma(
    const ushort* __restrict__ h_bf, const ushort* __restrict__ bt,
    const float* __restrict__ bias, ushort* __restrict__ qkv, int M)
{
    __shared__ __align__(16) ushort As[128 * 32];   // 128 rows x 64B
    __shared__ __align__(16) ushort Bs[128 * 32];

    const int bm = blockIdx.x * 128;
    const int bn = blockIdx.y * 128;
    const int t    = threadIdx.x;
    const int lane = t & 63;
    const int wid  = t >> 6;
    const int wm   = wid >> 1;
    const int wn   = wid & 1;
    const int fr   = lane & 15;

    // staging geometry: this lane covers (row_local, chunk) within its wave's
    // 16-row slab; global chunk is XOR-swizzled.
    const int srow0 = wid * 32 + (lane >> 2);        // call 0 row
    const int srow1 = srow0 + 16;                    // call 1 row
    const int g0 = (lane & 3) ^ (srow0 & 3);         // global chunk, call 0
    const int g1 = (lane & 3) ^ (srow1 & 3);         // global chunk, call 1
    const int ga0 = min(bm + srow0, M - 1);
    const int ga1 = min(bm + srow1, M - 1);
    // ds_read chunk for fragments: (lane>>4) ^ (fr&3), same for all frags
    const int rchunk = ((lane >> 4) ^ (fr & 3)) * 8; // in ushort units

    f32x4 acc[4][4];
    #pragma unroll
    for (int i = 0; i < 4; ++i)
        #pragma unroll
        for (int j = 0; j < 4; ++j)
            acc[i][j] = (f32x4){0.f, 0.f, 0.f, 0.f};

    for (int k0 = 0; k0 < DIM; k0 += 32) {
        // ---- stage A and B tiles via global_load_lds ----
        GLOAD_LDS16(h_bf + (size_t)ga0 * 256 + k0 + g0 * 8, As + (wid * 32) * 32);
        GLOAD_LDS16(h_bf + (size_t)ga1 * 256 + k0 + g1 * 8, As + (wid * 32 + 16) * 32);
        GLOAD_LDS16(bt + (size_t)(bn + srow0) * 256 + k0 + g0 * 8, Bs + (wid * 32) * 32);
        GLOAD_LDS16(bt + (size_t)(bn + srow1) * 256 + k0 + g1 * 8, Bs + (wid * 32 + 16) * 32);
        asm volatile("s_waitcnt vmcnt(0)" ::: "memory");
        __syncthreads();

        bs8 af[4], bf_[4];
        #pragma unroll
        for (int f = 0; f < 4; ++f) {
            af[f]  = *(const bs8*)(As + (wm * 64 + f * 16 + fr) * 32 + rchunk);
            bf_[f] = *(const bs8*)(Bs + (wn * 64 + f * 16 + fr) * 32 + rchunk);
        }
        #pragma unroll
        for (int fm = 0; fm < 4; ++fm)
            #pragma unroll
            for (int fn = 0; fn < 4; ++fn)
                MFMA16(acc[fm][fn], af[fm], bf_[fn]);

        __syncthreads();
    }

    asm volatile("s_nop 7\n\ts_nop 7\n\ts_nop 7" ::: );

    // ---- epilogue: C frag layout col=lane&15, row=(lane>>4)*4+reg ----
    #pragma unroll
    for (int fm = 0; fm < 4; ++fm) {
        const int rowbase = bm + wm * 64 + fm * 16 + (lane >> 4) * 4;
        #pragma unroll
        for (int fn = 0; fn < 4; ++fn) {
            const int col = bn + wn * 64 + fn * 16 + fr;
            float bv = (col >= 512) ? bias[col - 512] : 0.f;
            #pragma unroll
            for (int r = 0; r < 4; ++r) {
                const int row = rowbase + r;
                if (row < M)
                    qkv[(size_t)row * NQKV + col] = f2bf(acc[fm][fn][r] + bv);
            }
        }
    }
}

// ---------------------------------------------------------------------------
// K2: per-dst degree count
// ---------------------------------------------------------------------------
__global__ __launch_bounds__(256) void deg_count(
    const int* __restrict__ dst, int* __restrict__ deg, int E)
{
    const int e = blockIdx.x * 256 + threadIdx.x;
    if (e < E) atomicAdd(&deg[dst[e]], 1);
}

// ---------------------------------------------------------------------------
// K3: single block shuffle-scan deg -> row_ptr
// ---------------------------------------------------------------------------
__global__ __launch_bounds__(1024) void scan_rowptr(
    const int* __restrict__ deg, int* __restrict__ row_ptr, int N)
{
    const int tid  = threadIdx.x;
    const int lane = tid & 63;
    const int wv   = tid >> 6;

    if (tid == 0) row_ptr[0] = 0;

    __shared__ int woff[17];
    __shared__ int carryS;
    if (tid == 0) carryS = 0;
    __syncthreads();

    for (int base = 0; base < N; base += 4096) {
        int x[4], pre[4];
        int run = 0;
        #pragma unroll
        for (int j = 0; j < 4; ++j) {
            const int i = base + tid * 4 + j;
            const int v = (i < N) ? deg[i] : 0;
            pre[j] = run; x[j] = v; run += v;
        }
        int incl = run;
        #pragma unroll
        for (int off = 1; off < 64; off <<= 1) {
            int y = __shfl_up(incl, off);
            if (lane >= off) incl += y;
        }
        const int wex = incl - run;
        if (lane == 63) woff[wv] = incl;
        __syncthreads();
        if (wv == 0) {
            int wtot = (lane < 16) ? woff[lane] : 0;
            int winc = wtot;
            #pragma unroll
            for (int off = 1; off < 16; off <<= 1) {
                int y = __shfl_up(winc, off);
                if (lane >= off) winc += y;
            }
            if (lane < 16) woff[lane] = winc - wtot;
            if (lane == 15) woff[16] = winc;
        }
        __syncthreads();
        const int basev = carryS + woff[wv] + wex;
        #pragma unroll
        for (int j = 0; j < 4; ++j) {
            const int i = base + tid * 4 + j;
            if (i < N) row_ptr[i + 1] = basev + pre[j] + x[j];
        }
        __syncthreads();
        if (tid == 0) carryS += woff[16];
        __syncthreads();
    }
}

// ---------------------------------------------------------------------------
// K4: scatter edges into CSR order; pack {src, dst, orig_e}
// ---------------------------------------------------------------------------
__global__ __launch_bounds__(256) void scatter_edges(
    const int* __restrict__ src, const int* __restrict__ dst,
    const int* __restrict__ row_ptr, int* __restrict__ cursor,
    int4* __restrict__ edata, int E)
{
    const int e = blockIdx.x * 256 + threadIdx.x;
    if (e < E) {
        const int d = dst[e];
        const int pos = row_ptr[d] + atomicAdd(&cursor[d], 1);
        edata[pos] = make_int4(src[e], d, e, 0);
    }
}

// ---------------------------------------------------------------------------
// K5: per-edge raw score in CSR order.  Half-wave (32 lanes, uint4=16B/lane)
// per edge; 8 edges per iteration -> 4 q + 4 k loads in flight per lane.
// ---------------------------------------------------------------------------
__global__ __launch_bounds__(256) void edge_dot_csr(
    const ushort* __restrict__ qkv, const int4* __restrict__ edata,
    float* __restrict__ a_rawc, double* __restrict__ partials, int E)
{
    const int lane = threadIdx.x & 63;
    const int wid  = threadIdx.x >> 6;
    const int lq   = lane & 31;        // lane within half-wave
    const int hh   = lane >> 5;        // half-wave id (0/1)
    const int w    = blockIdx.x * 4 + wid;
    const int nw   = gridDim.x * 4;
    const int chunk = (E + nw - 1) / nw;
    const int p0 = min(E, w * chunk);
    const int p1 = min(E, p0 + chunk);

    double lsum = 0.0, lsum2 = 0.0;
    int p = p0;

    for (; p + 8 <= p1; p += 8) {
        const int4 ed0 = edata[p     + hh];
        const int4 ed1 = edata[p + 2 + hh];
        const int4 ed2 = edata[p + 4 + hh];
        const int4 ed3 = edata[p + 6 + hh];
        uint4 q0 = *(const uint4*)(qkv + (size_t)ed0.x * NQKV + lq * 8);
        uint4 q1 = *(const uint4*)(qkv + (size_t)ed1.x * NQKV + lq * 8);
        uint4 q2 = *(const uint4*)(qkv + (size_t)ed2.x * NQKV + lq * 8);
        uint4 q3 = *(const uint4*)(qkv + (size_t)ed3.x * NQKV + lq * 8);
        uint4 k0 = *(const uint4*)(qkv + (size_t)ed0.y * NQKV + 256 + lq * 8);
        uint4 k1 = *(const uint4*)(qkv + (size_t)ed1.y * NQKV + 256 + lq * 8);
        uint4 k2 = *(const uint4*)(qkv + (size_t)ed2.y * NQKV + 256 + lq * 8);
        uint4 k3 = *(const uint4*)(qkv + (size_t)ed3.y * NQKV + 256 + lq * 8);
        float d0 = dotu4(q0, k0);
        float d1 = dotu4(q1, k1);
        float d2 = dotu4(q2, k2);
        float d3 = dotu4(q3, k3);
        #pragma unroll
        for (int off = 16; off; off >>= 1) {
            d0 += __shfl_xor(d0, off);
            d1 += __shfl_xor(d1, off);
            d2 += __shfl_xor(d2, off);
            d3 += __shfl_xor(d3, off);
        }
        if (lq == 0) {
            a_rawc[p     + hh] = d0;
            a_rawc[p + 2 + hh] = d1;
            a_rawc[p + 4 + hh] = d2;
            a_rawc[p + 6 + hh] = d3;
            lsum  += (double)d0 + (double)d1 + (double)d2 + (double)d3;
            lsum2 += (double)d0 * d0 + (double)d1 * d1
                   + (double)d2 * d2 + (double)d3 * d3;
        }
    }
    for (; p + 2 <= p1; p += 2) {
        const int4 ed0 = edata[p + hh];
        uint4 q0 = *(const uint4*)(qkv + (size_t)ed0.x * NQKV + lq * 8);
        uint4 k0 = *(const uint4*)(qkv + (size_t)ed0.y * NQKV + 256 + lq * 8);
        float d0 = dotu4(q0, k0);
        #pragma unroll
        for (int off = 16; off; off >>= 1) d0 += __shfl_xor(d0, off);
        if (lq == 0) {
            a_rawc[p + hh] = d0;
            lsum  += (double)d0;
            lsum2 += (double)d0 * d0;
        }
    }
    if (p < p1) {   // single tail edge: both half-waves load it, half 0 writes
        const int4 ed0 = edata[p];
        uint4 q0 = *(const uint4*)(qkv + (size_t)ed0.x * NQKV + lq * 8);
        uint4 k0 = *(const uint4*)(qkv + (size_t)ed0.y * NQKV + 256 + lq * 8);
        float d0 = dotu4(q0, k0);
        #pragma unroll
        for (int off = 16; off; off >>= 1) d0 += __shfl_xor(d0, off);
        if (lane == 0) {
            a_rawc[p] = d0;
            lsum  += (double)d0;
            lsum2 += (double)d0 * d0;
        }
    }

    // combine the two half-wave accumulators (lanes 0 and 32) onto lane 0
    lsum  += __shfl_xor(lsum, 32);
    lsum2 += __shfl_xor(lsum2, 32);

    __shared__ double bsum[4], bsum2[4];
    if (lane == 0) { bsum[wid] = lsum; bsum2[wid] = lsum2; }
    __syncthreads();
    if (threadIdx.x == 0) {
        partials[blockIdx.x]             = bsum[0] + bsum[1] + bsum[2] + bsum[3];
        partials[gridDim.x + blockIdx.x] = bsum2[0] + bsum2[1] + bsum2[2] + bsum2[3];
    }
}

// ---------------------------------------------------------------------------
// K6: reduce stat partials -> coef {mean, 1/(std*T)}
// ---------------------------------------------------------------------------
__global__ __launch_bounds__(256) void finalize_coef(
    const double* __restrict__ partials, float* __restrict__ coef, int E)
{
    __shared__ double red[256];
    const int tid = threadIdx.x;
    double s1 = 0.0, s2 = 0.0;
    for (int i = tid; i < STAT_BLOCKS; i += 256) {
        s1 += partials[i];
        s2 += partials[STAT_BLOCKS + i];
    }
    red[tid] = s1;
    __syncthreads();
    for (int off = 128; off; off >>= 1) {
        if (tid < off) red[tid] += red[tid + off];
        __syncthreads();
    }
    const double tot1 = red[0];
    __syncthreads();
    red[tid] = s2;
    __syncthreads();
    for (int off = 128; off; off >>= 1) {
        if (tid < off) red[tid] += red[tid + off];
        __syncthreads();
    }
    if (tid == 0) {
        const double mean = tot1 / (double)E;
        const double var  = red[0] / (double)E - mean * mean;
        coef[0] = (float)mean;
        coef[1] = (float)(1.0 / (sqrt(var) * 0.5));   // /std /TEMPERATURE
    }
}

// ---------------------------------------------------------------------------
// K7: fused per-node softmax + aggregation.  WAVE-PER-NODE: each wave owns
// one node end-to-end -> zero block barriers, no cross-wave combine, no
// inter-node load-imbalance coupling.  Weights cached in per-wave LDS; gather
// is 4-deep unrolled with lane covering 4 cols (ushort4, 512B/row coalesced).
// ---------------------------------------------------------------------------
__global__ __launch_bounds__(256) void agg_fused(
    const ushort* __restrict__ qkv, const float* __restrict__ a_rawc,
    const int4* __restrict__ edata, const int* __restrict__ row_ptr,
    const float* __restrict__ coef,
    float* __restrict__ out, float* __restrict__ a_out, int N)
{
    const int lane = threadIdx.x & 63;
    const int wv   = threadIdx.x >> 6;
    const int node = blockIdx.x * 4 + wv;
    if (node >= N) return;          // safe: no block-wide barriers below

    const int s   = row_ptr[node];
    const int deg = row_ptr[node + 1] - s;
    const float mean = coef[0];
    const float mul  = coef[1];

    __shared__ float wbuf_s[4][128];
    __shared__ int   sbuf_s[4][128];
    float* wbuf = wbuf_s[wv];
    int*   sbuf = sbuf_s[wv];

    // ---- phase 1: softmax denominator (scores contiguous; |x| bounded) ----
    float lsum = 0.f;
    for (int j = lane; j < deg; j += 64)
        lsum += __expf((a_rawc[s + j] - mean) * mul);
    #pragma unroll
    for (int off = 32; off; off >>= 1) lsum += __shfl_xor(lsum, off);
    const float rcp = 1.0f / lsum;

    // ---- phase 2: weights to LDS + a_out, then weighted v-gather ----
    float4 acc = make_float4(0.f, 0.f, 0.f, 0.f);
    for (int b0 = 0; b0 < deg; b0 += 128) {
        const int bc = min(128, deg - b0);
        for (int j = lane; j < bc; j += 64) {
            const int4 ed = edata[s + b0 + j];
            const float wgt = __expf((a_rawc[s + b0 + j] - mean) * mul) * rcp;
            wbuf[j] = wgt;
            sbuf[j] = ed.x;
            a_out[ed.z] = wgt;
        }
        // wave-internal LDS write->read ordering (no block barrier needed)
        asm volatile("s_waitcnt lgkmcnt(0)" ::: "memory");
        __builtin_amdgcn_sched_barrier(0);

        int j = 0;
        for (; j + 4 <= bc; j += 4) {
            const float w0 = wbuf[j],     w1 = wbuf[j + 1];
            const float w2 = wbuf[j + 2], w3 = wbuf[j + 3];
            const int   s0 = sbuf[j],     s1 = sbuf[j + 1];
            const int   s2 = sbuf[j + 2], s3 = sbuf[j + 3];
            ushort4 v0 = *(const ushort4*)(qkv + (size_t)s0 * NQKV + 512 + lane * 4);
            ushort4 v1 = *(const ushort4*)(qkv + (size_t)s1 * NQKV + 512 + lane * 4);
            ushort4 v2 = *(const ushort4*)(qkv + (size_t)s2 * NQKV + 512 + lane * 4);
            ushort4 v3 = *(const ushort4*)(qkv + (size_t)s3 * NQKV + 512 + lane * 4);
            acc.x += w0 * bf2f(v0.x) + w1 * bf2f(v1.x) + w2 * bf2f(v2.x) + w3 * bf2f(v3.x);
            acc.y += w0 * bf2f(v0.y) + w1 * bf2f(v1.y) + w2 * bf2f(v2.y) + w3 * bf2f(v3.y);
            acc.z += w0 * bf2f(v0.z) + w1 * bf2f(v1.z) + w2 * bf2f(v2.z) + w3 * bf2f(v3.z);
            acc.w += w0 * bf2f(v0.w) + w1 * bf2f(v1.w) + w2 * bf2f(v2.w) + w3 * bf2f(v3.w);
        }
        for (; j < bc; ++j) {
            const float w0 = wbuf[j];
            const int   s0 = sbuf[j];
            ushort4 v0 = *(const ushort4*)(qkv + (size_t)s0 * NQKV + 512 + lane * 4);
            acc.x += w0 * bf2f(v0.x);
            acc.y += w0 * bf2f(v0.y);
            acc.z += w0 * bf2f(v0.z);
            acc.w += w0 * bf2f(v0.w);
        }
    }

    *(float4*)&out[(size_t)node * DIM + lane * 4] = acc;
}

// ---------------------------------------------------------------------------
extern "C" void kernel_launch(void* const* d_in, const int* in_sizes, int n_in,
                              void* d_out, int out_size, void* d_ws, size_t ws_size,
                              hipStream_t stream)
{
    const float* h      = (const float*)d_in[0];
    const int*   src    = (const int*)d_in[1];
    const int*   dst    = (const int*)d_in[2];
    const float* attn_q = (const float*)d_in[3];
    const float* attn_k = (const float*)d_in[4];
    const float* W      = (const float*)d_in[5];
    const float* bias   = (const float*)d_in[6];

    const int N = in_sizes[0] / DIM;
    const int E = in_sizes[1];

    float* out   = (float*)d_out;
    float* a_out = out + (size_t)N * DIM;

    char* ws = (char*)d_ws;
    ushort* h_bf  = (ushort*)ws;
    int4*   edata = (int4*)ws;               // ALIAS: reuses h_bf after gemm
    ws += (size_t)N * DIM * 2;               // 25.6 MB (edata needs 12.8 MB)
    ushort* qkv   = (ushort*)ws; ws += (size_t)N * NQKV * 2;
    ushort* bt    = (ushort*)ws; ws += (size_t)NQKV * DIM * 2;
    float* a_rawc = (float*)ws;  ws += (size_t)E * 4;
    int* deg      = (int*)ws;    ws += (size_t)N * 4;
    int* cursor   = (int*)ws;    ws += (size_t)N * 4;
    double* partials = (double*)ws; ws += (size_t)STAT_BLOCKS * 2 * 8;
    float* coef   = (float*)ws;  ws += 8;
    int* row_ptr  = (int*)ws;    ws += (size_t)(N + 1) * 4;

    hipMemsetAsync(deg,    0, (size_t)N * 4, stream);
    hipMemsetAsync(cursor, 0, (size_t)N * 4, stream);

    const int total8 = N * DIM / 8;
    conv_h<<<(total8 + 255) / 256, 256, 0, stream>>>(h, h_bf, total8);
    build_bt<<<NQKV, 256, 0, stream>>>(attn_q, attn_k, W, bt);

    dim3 gg((N + 127) / 128, NQKV / 128);
    gemm_qkv_mfma<<<gg, 256, 0, stream>>>(h_bf, bt, bias, qkv, N);

    deg_count<<<(E + 255) / 256, 256, 0, stream>>>(dst, deg, E);
    scan_rowptr<<<1, 1024, 0, stream>>>(deg, row_ptr, N);
    scatter_edges<<<(E + 255) / 256, 256, 0, stream>>>(src, dst, row_ptr, cursor, edata, E);
    edge_dot_csr<<<STAT_BLOCKS, 256, 0, stream>>>(qkv, edata, a_rawc, partials, E);
    finalize_coef<<<1, 256, 0, stream>>>(partials, coef, E);
    agg_fused<<<(N + 3) / 4, 256, 0, stream>>>(qkv, a_rawc, edata, row_ptr, coef, out, a_out, N);
}